// Round 9
// baseline (518.014 us; speedup 1.0000x reference)
//
#include <hip/hip_runtime.h>
#include <cstdint>
#include <cstddef>

static constexpr int B_ = 2, S_ = 2048, D_ = 1024, H_ = 16, HD_ = 64;

typedef float f32x4 __attribute__((ext_vector_type(4)));
typedef short bf16x8 __attribute__((ext_vector_type(8)));

__device__ __forceinline__ unsigned short f2bf(float f) {
    union { float f; unsigned int u; } v; v.f = f;
    unsigned int r = v.u + 0x7FFFu + ((v.u >> 16) & 1u);   // RNE
    return (unsigned short)(r >> 16);
}

// 5-op RNE pair pack: add per value, one v_perm_b32 to gather the two high
// halves. Bit-identical to f2bf(a) | f2bf(b)<<16. NO hardware cvt_pk
// (round-2 failure: v_cvt_pk_bf16_f32 is not RNE-equivalent).
__device__ __forceinline__ unsigned pack2bf(float a, float b) {
    union { float f; unsigned u; } va, vb; va.f = a; vb.f = b;
    unsigned ra = va.u + 0x7FFFu + ((va.u >> 16) & 1u);
    unsigned rb = vb.u + 0x7FFFu + ((vb.u >> 16) & 1u);
    return __builtin_amdgcn_perm(rb, ra, 0x07060302u);
}

// async global->LDS, 16B per lane. LDS dest = wave-uniform base + lane*16.
__device__ __forceinline__ void gload_lds16(const void* g, void* l) {
    __builtin_amdgcn_global_load_lds(
        (const __attribute__((address_space(1))) void*)g,
        (__attribute__((address_space(3))) void*)l, 16, 0, 0);
}

// ---------------------------------------------------------------------------
// Fused prep: [0,2048) cast x->bf16 | [2048,4096) mask int32->u8 (0xFF/0x00) |
// [4096,4864) W transpose+cast. (unchanged, proven)
// ---------------------------------------------------------------------------
__global__ __launch_bounds__(256)
void prep(const float* __restrict__ x, unsigned short* __restrict__ xo,
          const int* __restrict__ m, unsigned char* __restrict__ mo,
          const float* __restrict__ Wq, const float* __restrict__ Wk,
          const float* __restrict__ Wv, unsigned short* __restrict__ wt) {
    __shared__ unsigned short Ts[64][72];
    const int bid = blockIdx.x, t = threadIdx.x;
    if (bid < 2048) {
        size_t i = ((size_t)bid * 256 + t) * 8;
        float4 a = *(const float4*)(x + i);
        float4 c = *(const float4*)(x + i + 4);
        uint4 r;
        r.x = pack2bf(a.x, a.y); r.y = pack2bf(a.z, a.w);
        r.z = pack2bf(c.x, c.y); r.w = pack2bf(c.z, c.w);
        *(uint4*)(xo + i) = r;
    } else if (bid < 4096) {
        size_t i = ((size_t)(bid - 2048) * 256 + t) * 16;
        uint4 r;
        unsigned w[4];
        #pragma unroll
        for (int g = 0; g < 4; ++g) {
            int4 v = *(const int4*)(m + i + g * 4);
            w[g] = (v.x ? 0xFFu : 0u) | (v.y ? 0xFF00u : 0u) |
                   (v.z ? 0xFF0000u : 0u) | (v.w ? 0xFF000000u : 0u);
        }
        r.x = w[0]; r.y = w[1]; r.z = w[2]; r.w = w[3];
        *(uint4*)(mo + i) = r;
    } else {
        const int tid = bid - 4096;            // 0..767
        const int mat = tid >> 8, tile = tid & 255;
        const float* __restrict__ W = (mat == 0) ? Wq : (mat == 1) ? Wk : Wv;
        unsigned short* __restrict__ o = wt + (size_t)mat * D_ * D_;
        const int n0 = (tile & 15) * 64, k0 = (tile >> 4) * 64;
        {
            const int nl = t & 63, kb = t >> 6;
            #pragma unroll
            for (int i = 0; i < 16; ++i) {
                int k = kb + i * 4;
                Ts[nl][k] = f2bf(W[(size_t)(k0 + k) * D_ + n0 + nl]);
            }
        }
        __syncthreads();
        {
            const int kl = t & 63, nb = t >> 6;
            #pragma unroll
            for (int i = 0; i < 16; ++i) {
                int n = nb + i * 4;
                o[(size_t)(n0 + n) * D_ + k0 + kl] = Ts[n][kl];
            }
        }
    }
}

// ---------------------------------------------------------------------------
// QKV GEMM, bf16 MFMA 16x16x32. 128x128 tile, BK=32, double-buffered DMA.
// 512 threads (8 waves, wave-tile 64x32), 24 waves/CU. (round-5, proven)
// ---------------------------------------------------------------------------
__global__ __launch_bounds__(512)
void qkv_gemm(const unsigned short* __restrict__ xb, const unsigned short* __restrict__ wt,
              const float* __restrict__ bq, const float* __restrict__ bk,
              const float* __restrict__ bv,
              unsigned short* __restrict__ qo, unsigned short* __restrict__ ko,
              unsigned short* __restrict__ vto) {
    const int bx = blockIdx.x;            // 0..23: mat*8 + ntile
    const int by = blockIdx.y;            // 0..31: mtile
    const int mat = bx >> 3;
    const int ncol0 = (bx & 7) * 128;
    const float* __restrict__ bias = (mat == 0) ? bq : (mat == 1) ? bk : bv;
    const unsigned short* __restrict__ Wm = wt + (size_t)mat * D_ * D_;

    __shared__ unsigned short As[2][128 * 32];
    __shared__ unsigned short Bs[2][128 * 32];

    const int t = threadIdx.x;
    const int w = t >> 6, lane = t & 63;
    const int l15 = lane & 15, quad = lane >> 4;
    const int mw = (w >> 2) * 64, nw = (w & 3) * 32;   // wave tile 64x32
    const int rowBase = by * 128;

    const int r16 = lane >> 2;                       // 0..15
    const int sslot = lane & 3;
    const int sg = (sslot ^ ((r16 >> 1) & 3)) * 8;   // staged global col (shorts)
    const int srow = w * 16 + r16;                   // staging row 0..127
    const int rcol = (quad ^ ((l15 >> 1) & 3)) * 8;  // fragment read col (shorts)

    f32x4 acc[4][2] = {};

    gload_lds16(xb + (size_t)(rowBase + srow) * D_ + sg, &As[0][w * 16 * 32]);
    gload_lds16(Wm + (size_t)(ncol0 + srow) * D_ + sg, &Bs[0][w * 16 * 32]);

    for (int it = 0; it < 32; ++it) {
        const int cur = it & 1;
        __syncthreads();
        if (it + 1 < 32) {
            const int ktn = (it + 1) * 32;
            gload_lds16(xb + (size_t)(rowBase + srow) * D_ + ktn + sg,
                        &As[cur ^ 1][w * 16 * 32]);
            gload_lds16(Wm + (size_t)(ncol0 + srow) * D_ + ktn + sg,
                        &Bs[cur ^ 1][w * 16 * 32]);
        }

        bf16x8 a[4], b[2];
        #pragma unroll
        for (int i = 0; i < 4; ++i)
            a[i] = *(const bf16x8*)&As[cur][(mw + i * 16 + l15) * 32 + rcol];
        #pragma unroll
        for (int j = 0; j < 2; ++j)
            b[j] = *(const bf16x8*)&Bs[cur][(nw + j * 16 + l15) * 32 + rcol];
        #pragma unroll
        for (int i = 0; i < 4; ++i)
            #pragma unroll
            for (int j = 0; j < 2; ++j)
                acc[i][j] = __builtin_amdgcn_mfma_f32_16x16x32_bf16(a[i], b[j], acc[i][j], 0, 0, 0);
    }

    if (mat < 2) {
        unsigned short* __restrict__ O = (mat == 0) ? qo : ko;
        const float osc = (mat == 0) ? 0.18033688011112443f : 1.0f;  // 0.125*log2(e)
        #pragma unroll
        for (int j = 0; j < 2; ++j) {
            const int col = ncol0 + nw + j * 16 + l15;
            const float bb = bias[col];
            #pragma unroll
            for (int i = 0; i < 4; ++i)
                #pragma unroll
                for (int r = 0; r < 4; ++r) {
                    const int m = rowBase + mw + i * 16 + quad * 4 + r;
                    O[(size_t)m * D_ + col] = f2bf((acc[i][j][r] + bb) * osc);
                }
        }
    } else {
        #pragma unroll
        for (int j = 0; j < 2; ++j) {
            const int col = ncol0 + nw + j * 16 + l15;
            const float bb = bias[col];
            const int hh = col >> 6, hd = col & 63;
            #pragma unroll
            for (int i = 0; i < 4; ++i) {
                const int m0 = rowBase + mw + i * 16 + quad * 4;
                const int bg = m0 >> 11, s0 = m0 & 2047;
                ushort4 pk;
                pk.x = f2bf(acc[i][j][0] + bb);
                pk.y = f2bf(acc[i][j][1] + bb);
                pk.z = f2bf(acc[i][j][2] + bb);
                pk.w = f2bf(acc[i][j][3] + bb);
                *(ushort4*)&vto[(((size_t)bg * H_ + hh) * HD_ + hd) * S_ + s0] = pk;
            }
        }
    }
}

// ---------------------------------------------------------------------------
// Flash attention, bf16 MFMA, S^T orientation, Q in registers.
// KEY-HALF GRID SPLIT: grid 1024 = (16 h, 16 qt x 2 half, 2 b). Each block
// owns 1024 keys (half*1024..+1024), 16 iters — total staged bytes UNCHANGED
// (same K/V rows staged by the same number of blocks), but 3 blocks/CU
// resident (48KB LDS) -> 24 waves/CU vs 16. Blocks write unnormalized
// partial O (f32) + row-sums; attn_reduce sums halves and normalizes.
// Internals = round-8 proven kernel (wave pair splits 64-key tile, Ps
// granule-disjoint, XOR swizzles, perm/bfi mask). Main loop unrolled x2
// (literal cur) so all swizzled LDS addresses are loop-invariant & hoisted.
// launch_bounds(512,6): VGPR cap 85 >= 60 used (r6 spill lesson).
// Numerics: FP32 add reorder only (half-split; key-split passed r6/r8).
// ---------------------------------------------------------------------------
__global__ __launch_bounds__(512, 6)
void attn_mfma(const unsigned short* __restrict__ qmat,
               const unsigned short* __restrict__ kmat,
               const unsigned short* __restrict__ vtg,
               const unsigned char* __restrict__ msk,
               float* __restrict__ opart, float* __restrict__ lspart) {
    const int h = blockIdx.x, yy = blockIdx.y, b = blockIdx.z;
    const int qt = yy >> 1, half = yy & 1;
    const int t = threadIdx.x, w = t >> 6, lane = t & 63;
    const int l15 = lane & 15, quad = lane >> 4;
    const int q0 = qt * 128;

    __shared__ __align__(16) char smem[49152];
    unsigned short* const Ksm = (unsigned short*)smem;            // [2][64*64]
    unsigned short* const Vsm = (unsigned short*)(smem + 16384);  // [2][64*64]
    unsigned short* const Psm = (unsigned short*)(smem + 32768);  // [128*64]

    const size_t bh = (size_t)b * S_ * D_ + (size_t)h * HD_;
    const unsigned short* __restrict__ qp = qmat + bh;
    const unsigned short* __restrict__ kp = kmat + bh + (size_t)half * 1024 * D_;
    const unsigned short* __restrict__ vp = vtg + ((size_t)b * H_ + h) * HD_ * S_ + half * 1024;
    const unsigned char* __restrict__ mb = msk + (size_t)b * S_ * S_ + half * 1024;

    const int rs = lane >> 3, sslot = lane & 7;
    const int sg = (sslot ^ rs) * 8;         // staged global granule col (shorts)
    const int srow = w * 8 + rs;             // staging row 0..63 (8 rows/wave)

    const int qs = w >> 1;                   // q-substrip 0..3 (32 rows each)
    const int kw = (w & 1) * 32;             // wave's key half offset
    const int kst = w & 1;                   // key-half granule base for PV
    const int sw7 = l15 & 7;                 // row swizzle key (all rows &7)

    // Q fragments in registers (loop-invariant): 2 qrow strips x 2 d-halves
    bf16x8 qfr[2][2];
    #pragma unroll
    for (int nt = 0; nt < 2; ++nt)
        #pragma unroll
        for (int dk = 0; dk < 2; ++dk)
            qfr[nt][dk] = *(const bf16x8*)(qp +
                (size_t)(q0 + qs * 32 + nt * 16 + l15) * D_ + dk * 32 + quad * 8);

    f32x4 accO[2][4] = {};
    f32x4 lsA[2] = {};
    bf16x8 ones;
    #pragma unroll
    for (int i = 0; i < 8; ++i) ones[i] = (short)0x3F80;   // bf16 1.0

    // prologue: stage tile 0 into buffer 0 (one 16B DMA per thread per matrix)
    gload_lds16(kp + (size_t)srow * D_ + sg, Ksm + w * 8 * 64);
    gload_lds16(vp + (size_t)srow * S_ + sg, Vsm + w * 8 * 64);

#define ATTN_STEP(IT, CUR)                                                     \
    do {                                                                       \
        const int kt = (IT) * 64;                                              \
        __syncthreads();                                                       \
        unsigned mu[2][2];                                                     \
        _Pragma("unroll")                                                      \
        for (int nt = 0; nt < 2; ++nt) {                                       \
            const unsigned char* __restrict__ mrow =                           \
                mb + (size_t)(q0 + qs * 32 + nt * 16 + l15) * S_ + kt + kw;    \
            mu[nt][0] = *(const unsigned*)(mrow + quad * 4);                   \
            mu[nt][1] = *(const unsigned*)(mrow + 16 + quad * 4);              \
        }                                                                      \
        if ((IT) + 1 < 16) {                                                   \
            const int ktn = kt + 64;                                           \
            gload_lds16(kp + (size_t)(ktn + srow) * D_ + sg,                   \
                        Ksm + ((CUR) ^ 1) * 4096 + w * 8 * 64);                \
            gload_lds16(vp + (size_t)srow * S_ + ktn + sg,                     \
                        Vsm + ((CUR) ^ 1) * 4096 + w * 8 * 64);                \
        }                                                                      \
        f32x4 sc[2][2] = {};                                                   \
        _Pragma("unroll")                                                      \
        for (int dk = 0; dk < 2; ++dk) {                                       \
            bf16x8 kfr[2];                                                     \
            _Pragma("unroll")                                                  \
            for (int mt = 0; mt < 2; ++mt) {                                   \
                const int R = kw + mt * 16 + l15;                              \
                kfr[mt] = *(const bf16x8*)&Ksm[(CUR) * 4096 + R * 64 +         \
                                               (((dk * 4 + quad) ^ sw7) * 8)]; \
            }                                                                  \
            __builtin_amdgcn_s_setprio(1);                                     \
            _Pragma("unroll")                                                  \
            for (int nt = 0; nt < 2; ++nt)                                     \
                _Pragma("unroll")                                              \
                for (int mt = 0; mt < 2; ++mt)                                 \
                    sc[nt][mt] = __builtin_amdgcn_mfma_f32_16x16x32_bf16(      \
                        kfr[mt], qfr[nt][dk], sc[nt][mt], 0, 0, 0);            \
            __builtin_amdgcn_s_setprio(0);                                     \
        }                                                                      \
        _Pragma("unroll")                                                      \
        for (int nt = 0; nt < 2; ++nt) {                                       \
            const int qr = qs * 32 + nt * 16 + l15;                            \
            _Pragma("unroll")                                                  \
            for (int mt = 0; mt < 2; ++mt) {                                   \
                const int mtg = kst * 2 + mt;                                  \
                unsigned p0 = pack2bf(__builtin_amdgcn_exp2f(sc[nt][mt][0]),   \
                                      __builtin_amdgcn_exp2f(sc[nt][mt][1]));  \
                unsigned p1 = pack2bf(__builtin_amdgcn_exp2f(sc[nt][mt][2]),   \
                                      __builtin_amdgcn_exp2f(sc[nt][mt][3]));  \
                const unsigned m0 =                                            \
                    __builtin_amdgcn_perm(0u, mu[nt][mt], 0x01010000u);        \
                const unsigned m1 =                                            \
                    __builtin_amdgcn_perm(0u, mu[nt][mt], 0x03030202u);        \
                p0 = (m0 & 0x3F803F80u) | (~m0 & p0);                          \
                p1 = (m1 & 0x3F803F80u) | (~m1 & p1);                          \
                uint2 pk2; pk2.x = p0; pk2.y = p1;                             \
                *(uint2*)((char*)Psm + qr * 128 +                              \
                          (((2 * mtg + (quad >> 1)) ^ sw7) * 16) +             \
                          (quad & 1) * 8) = pk2;                               \
            }                                                                  \
        }                                                                      \
        {                                                                      \
            bf16x8 vfr[4];                                                     \
            _Pragma("unroll")                                                  \
            for (int dt = 0; dt < 4; ++dt) {                                   \
                const int R = dt * 16 + l15;                                   \
                vfr[dt] = *(const bf16x8*)&Vsm[(CUR) * 4096 + R * 64 +         \
                                               (((kst * 4 + quad) ^ sw7) * 8)];\
            }                                                                  \
            _Pragma("unroll")                                                  \
            for (int nt = 0; nt < 2; ++nt) {                                   \
                const int qr = qs * 32 + nt * 16 + l15;                        \
                bf16x8 pfr = *(const bf16x8*)((const char*)Psm + qr * 128 +    \
                                              (((kst * 4 + quad) ^ sw7) * 16));\
                __builtin_amdgcn_s_setprio(1);                                 \
                _Pragma("unroll")                                              \
                for (int dt = 0; dt < 4; ++dt)                                 \
                    accO[nt][dt] = __builtin_amdgcn_mfma_f32_16x16x32_bf16(    \
                        pfr, vfr[dt], accO[nt][dt], 0, 0, 0);                  \
                lsA[nt] = __builtin_amdgcn_mfma_f32_16x16x32_bf16(             \
                    pfr, ones, lsA[nt], 0, 0, 0);                              \
                __builtin_amdgcn_s_setprio(0);                                 \
            }                                                                  \
        }                                                                      \
    } while (0)

    for (int io = 0; io < 8; ++io) {
        ATTN_STEP(2 * io, 0);
        ATTN_STEP(2 * io + 1, 1);
    }
#undef ATTN_STEP

    // pair reduction: odd wave's partial accO/lsA -> even wave via smem
    // (Ks/Vs/Ps dead; 8 strips x 64 lanes x 20 floats = 40960B <= 49152B)
    __syncthreads();
    float* const Red = (float*)smem;
    if (w & 1) {
        #pragma unroll
        for (int nt = 0; nt < 2; ++nt) {
            const int pidx = ((qs * 2 + nt) * 64 + lane) * 20;
            #pragma unroll
            for (int dt = 0; dt < 4; ++dt)
                *(f32x4*)&Red[pidx + dt * 4] = accO[nt][dt];
            *(f32x4*)&Red[pidx + 16] = lsA[nt];
        }
    }
    __syncthreads();
    if (!(w & 1)) {
        float* __restrict__ op = opart +
            (((size_t)half * B_ + b) * S_ + q0) * D_ + (size_t)h * HD_;
        #pragma unroll
        for (int nt = 0; nt < 2; ++nt) {
            const int pidx = ((qs * 2 + nt) * 64 + lane) * 20;
            #pragma unroll
            for (int dt = 0; dt < 4; ++dt)
                accO[nt][dt] += *(const f32x4*)&Red[pidx + dt * 4];
            lsA[nt] += *(const f32x4*)&Red[pidx + 16];

            #pragma unroll
            for (int r = 0; r < 4; ++r) {
                const int row = qs * 32 + nt * 16 + quad * 4 + r;
                #pragma unroll
                for (int dt = 0; dt < 4; ++dt)
                    op[(size_t)row * D_ + dt * 16 + l15] = accO[nt][dt][r];
            }
            if (l15 == 0) {
                #pragma unroll
                for (int r = 0; r < 4; ++r) {
                    const int row = qs * 32 + nt * 16 + quad * 4 + r;
                    lspart[(((size_t)half * B_ + b) * H_ + h) * S_ + q0 + row] =
                        lsA[nt][r];
                }
            }
        }
    }
}

// ---------------------------------------------------------------------------
// Reduce: out = (Op[0]+Op[1]) / (Ls[0]+Ls[1]). 4M f32, float4/thread.
// ---------------------------------------------------------------------------
__global__ __launch_bounds__(256)
void attn_reduce(const float* __restrict__ Op, const float* __restrict__ Ls,
                 float* __restrict__ out) {
    const size_t i = ((size_t)blockIdx.x * 256 + threadIdx.x) * 4;
    const size_t HALF = (size_t)B_ * S_ * D_;   // 4M floats
    float4 p0 = *(const float4*)(Op + i);
    float4 p1 = *(const float4*)(Op + HALF + i);
    const int rowg = (int)(i >> 10);            // b*S + row
    const int col = (int)(i & 1023);
    const int b = rowg >> 11, row = rowg & 2047, h = col >> 6;
    const float l = Ls[((size_t)b * H_ + h) * S_ + row] +
                    Ls[((size_t)(B_ + b) * H_ + h) * S_ + row];
    const float inv = 1.0f / l;
    float4 o;
    o.x = (p0.x + p1.x) * inv;
    o.y = (p0.y + p1.y) * inv;
    o.z = (p0.z + p1.z) * inv;
    o.w = (p0.w + p1.w) * inv;
    *(float4*)(out + i) = o;
}

extern "C" void kernel_launch(void* const* d_in, const int* in_sizes, int n_in,
                              void* d_out, int out_size, void* d_ws, size_t ws_size,
                              hipStream_t stream) {
    (void)in_sizes; (void)n_in; (void)out_size; (void)ws_size;
    const float* x    = (const float*)d_in[0];
    const int*   mask = (const int*)d_in[1];
    const float* Wq   = (const float*)d_in[2];
    const float* bq   = (const float*)d_in[3];
    const float* Wk   = (const float*)d_in[4];
    const float* bk   = (const float*)d_in[5];
    const float* Wv   = (const float*)d_in[6];
    const float* bv   = (const float*)d_in[7];
    float* out = (float*)d_out;

    const size_t M1 = (size_t)1024 * 1024;
    unsigned short* xb  = (unsigned short*)d_ws;      // 4M bf16
    unsigned short* wtb = xb + 4 * M1;                // 3M bf16
    unsigned short* qb  = wtb + 3 * M1;               // 4M bf16
    unsigned short* kb  = qb + 4 * M1;                // 4M bf16
    unsigned short* vtb = kb + 4 * M1;                // 4M bf16 (transposed V)
    unsigned char*  mk  = (unsigned char*)(vtb + 4 * M1);  // 8M u8 (0xFF/0x00)
    float* opart = (float*)(mk + 8 * M1);             // 2 x B*S*D f32 = 32MB
    float* lspart = opart + 2 * (size_t)B_ * S_ * D_; // 2 x B*H*S f32 = 512KB

    prep<<<4864, 256, 0, stream>>>(x, xb, mask, mk, Wq, Wk, Wv, wtb);
    qkv_gemm<<<dim3(24, 32), 512, 0, stream>>>(xb, wtb, bq, bk, bv, qb, kb, vtb);
    attn_mfma<<<dim3(16, 32, 2), 512, 0, stream>>>(qb, kb, vtb, mk, opart, lspart);
    attn_reduce<<<4096, 256, 0, stream>>>(opart, lspart, out);
}

// Round 10
// 236.441 us; speedup vs baseline: 2.1909x; 2.1909x over previous
//
#include <hip/hip_runtime.h>
#include <cstdint>
#include <cstddef>

static constexpr int B_ = 2, S_ = 2048, D_ = 1024, H_ = 16, HD_ = 64;

typedef float f32x4 __attribute__((ext_vector_type(4)));
typedef short bf16x8 __attribute__((ext_vector_type(8)));

__device__ __forceinline__ unsigned short f2bf(float f) {
    union { float f; unsigned int u; } v; v.f = f;
    unsigned int r = v.u + 0x7FFFu + ((v.u >> 16) & 1u);   // RNE
    return (unsigned short)(r >> 16);
}

// 5-op RNE pair pack: add per value, one v_perm_b32 to gather the two high
// halves. Bit-identical to f2bf(a) | f2bf(b)<<16. NO hardware cvt_pk
// (round-2 failure: v_cvt_pk_bf16_f32 is not RNE-equivalent).
__device__ __forceinline__ unsigned pack2bf(float a, float b) {
    union { float f; unsigned u; } va, vb; va.f = a; vb.f = b;
    unsigned ra = va.u + 0x7FFFu + ((va.u >> 16) & 1u);
    unsigned rb = vb.u + 0x7FFFu + ((vb.u >> 16) & 1u);
    return __builtin_amdgcn_perm(rb, ra, 0x07060302u);
}

// async global->LDS, 16B per lane. LDS dest = wave-uniform base + lane*16.
__device__ __forceinline__ void gload_lds16(const void* g, void* l) {
    __builtin_amdgcn_global_load_lds(
        (const __attribute__((address_space(1))) void*)g,
        (__attribute__((address_space(3))) void*)l, 16, 0, 0);
}

// ---------------------------------------------------------------------------
// Fused prep: [0,2048) cast x->bf16 | [2048,4096) mask int32->u8 (0xFF/0x00) |
// [4096,4864) W transpose+cast. (unchanged, proven)
// ---------------------------------------------------------------------------
__global__ __launch_bounds__(256)
void prep(const float* __restrict__ x, unsigned short* __restrict__ xo,
          const int* __restrict__ m, unsigned char* __restrict__ mo,
          const float* __restrict__ Wq, const float* __restrict__ Wk,
          const float* __restrict__ Wv, unsigned short* __restrict__ wt) {
    __shared__ unsigned short Ts[64][72];
    const int bid = blockIdx.x, t = threadIdx.x;
    if (bid < 2048) {
        size_t i = ((size_t)bid * 256 + t) * 8;
        float4 a = *(const float4*)(x + i);
        float4 c = *(const float4*)(x + i + 4);
        uint4 r;
        r.x = pack2bf(a.x, a.y); r.y = pack2bf(a.z, a.w);
        r.z = pack2bf(c.x, c.y); r.w = pack2bf(c.z, c.w);
        *(uint4*)(xo + i) = r;
    } else if (bid < 4096) {
        size_t i = ((size_t)(bid - 2048) * 256 + t) * 16;
        uint4 r;
        unsigned w[4];
        #pragma unroll
        for (int g = 0; g < 4; ++g) {
            int4 v = *(const int4*)(m + i + g * 4);
            w[g] = (v.x ? 0xFFu : 0u) | (v.y ? 0xFF00u : 0u) |
                   (v.z ? 0xFF0000u : 0u) | (v.w ? 0xFF000000u : 0u);
        }
        r.x = w[0]; r.y = w[1]; r.z = w[2]; r.w = w[3];
        *(uint4*)(mo + i) = r;
    } else {
        const int tid = bid - 4096;            // 0..767
        const int mat = tid >> 8, tile = tid & 255;
        const float* __restrict__ W = (mat == 0) ? Wq : (mat == 1) ? Wk : Wv;
        unsigned short* __restrict__ o = wt + (size_t)mat * D_ * D_;
        const int n0 = (tile & 15) * 64, k0 = (tile >> 4) * 64;
        {
            const int nl = t & 63, kb = t >> 6;
            #pragma unroll
            for (int i = 0; i < 16; ++i) {
                int k = kb + i * 4;
                Ts[nl][k] = f2bf(W[(size_t)(k0 + k) * D_ + n0 + nl]);
            }
        }
        __syncthreads();
        {
            const int kl = t & 63, nb = t >> 6;
            #pragma unroll
            for (int i = 0; i < 16; ++i) {
                int n = nb + i * 4;
                o[(size_t)(n0 + n) * D_ + k0 + kl] = Ts[n][kl];
            }
        }
    }
}

// ---------------------------------------------------------------------------
// QKV GEMM, bf16 MFMA 16x16x32. 128x128 tile, BK=32, double-buffered DMA.
// 512 threads (8 waves, wave-tile 64x32), 24 waves/CU. (round-5, proven)
// ---------------------------------------------------------------------------
__global__ __launch_bounds__(512)
void qkv_gemm(const unsigned short* __restrict__ xb, const unsigned short* __restrict__ wt,
              const float* __restrict__ bq, const float* __restrict__ bk,
              const float* __restrict__ bv,
              unsigned short* __restrict__ qo, unsigned short* __restrict__ ko,
              unsigned short* __restrict__ vto) {
    const int bx = blockIdx.x;            // 0..23: mat*8 + ntile
    const int by = blockIdx.y;            // 0..31: mtile
    const int mat = bx >> 3;
    const int ncol0 = (bx & 7) * 128;
    const float* __restrict__ bias = (mat == 0) ? bq : (mat == 1) ? bk : bv;
    const unsigned short* __restrict__ Wm = wt + (size_t)mat * D_ * D_;

    __shared__ unsigned short As[2][128 * 32];
    __shared__ unsigned short Bs[2][128 * 32];

    const int t = threadIdx.x;
    const int w = t >> 6, lane = t & 63;
    const int l15 = lane & 15, quad = lane >> 4;
    const int mw = (w >> 2) * 64, nw = (w & 3) * 32;   // wave tile 64x32
    const int rowBase = by * 128;

    const int r16 = lane >> 2;                       // 0..15
    const int sslot = lane & 3;
    const int sg = (sslot ^ ((r16 >> 1) & 3)) * 8;   // staged global col (shorts)
    const int srow = w * 16 + r16;                   // staging row 0..127
    const int rcol = (quad ^ ((l15 >> 1) & 3)) * 8;  // fragment read col (shorts)

    f32x4 acc[4][2] = {};

    gload_lds16(xb + (size_t)(rowBase + srow) * D_ + sg, &As[0][w * 16 * 32]);
    gload_lds16(Wm + (size_t)(ncol0 + srow) * D_ + sg, &Bs[0][w * 16 * 32]);

    for (int it = 0; it < 32; ++it) {
        const int cur = it & 1;
        __syncthreads();
        if (it + 1 < 32) {
            const int ktn = (it + 1) * 32;
            gload_lds16(xb + (size_t)(rowBase + srow) * D_ + ktn + sg,
                        &As[cur ^ 1][w * 16 * 32]);
            gload_lds16(Wm + (size_t)(ncol0 + srow) * D_ + ktn + sg,
                        &Bs[cur ^ 1][w * 16 * 32]);
        }

        bf16x8 a[4], b[2];
        #pragma unroll
        for (int i = 0; i < 4; ++i)
            a[i] = *(const bf16x8*)&As[cur][(mw + i * 16 + l15) * 32 + rcol];
        #pragma unroll
        for (int j = 0; j < 2; ++j)
            b[j] = *(const bf16x8*)&Bs[cur][(nw + j * 16 + l15) * 32 + rcol];
        #pragma unroll
        for (int i = 0; i < 4; ++i)
            #pragma unroll
            for (int j = 0; j < 2; ++j)
                acc[i][j] = __builtin_amdgcn_mfma_f32_16x16x32_bf16(a[i], b[j], acc[i][j], 0, 0, 0);
    }

    if (mat < 2) {
        unsigned short* __restrict__ O = (mat == 0) ? qo : ko;
        const float osc = (mat == 0) ? 0.18033688011112443f : 1.0f;  // 0.125*log2(e)
        #pragma unroll
        for (int j = 0; j < 2; ++j) {
            const int col = ncol0 + nw + j * 16 + l15;
            const float bb = bias[col];
            #pragma unroll
            for (int i = 0; i < 4; ++i)
                #pragma unroll
                for (int r = 0; r < 4; ++r) {
                    const int m = rowBase + mw + i * 16 + quad * 4 + r;
                    O[(size_t)m * D_ + col] = f2bf((acc[i][j][r] + bb) * osc);
                }
        }
    } else {
        #pragma unroll
        for (int j = 0; j < 2; ++j) {
            const int col = ncol0 + nw + j * 16 + l15;
            const float bb = bias[col];
            const int hh = col >> 6, hd = col & 63;
            #pragma unroll
            for (int i = 0; i < 4; ++i) {
                const int m0 = rowBase + mw + i * 16 + quad * 4;
                const int bg = m0 >> 11, s0 = m0 & 2047;
                ushort4 pk;
                pk.x = f2bf(acc[i][j][0] + bb);
                pk.y = f2bf(acc[i][j][1] + bb);
                pk.z = f2bf(acc[i][j][2] + bb);
                pk.w = f2bf(acc[i][j][3] + bb);
                *(ushort4*)&vto[(((size_t)bg * H_ + hh) * HD_ + hd) * S_ + s0] = pk;
            }
        }
    }
}

// ---------------------------------------------------------------------------
// Flash attention, bf16 MFMA, S^T orientation, Q in registers.
// KEY-HALF GRID SPLIT (round 9) with the launch-bounds fix: (512,4) — the
// round-8 proven cap (VGPR ~60, zero spill). Round 9's (512,6) made the
// compiler budget 40 VGPR to guarantee 6 waves/EU -> accumulator spills ->
// 1.68GB scratch traffic/dispatch. With 60 VGPR and 48KB LDS, runtime
// occupancy = 3 blocks/CU (LDS-limited) = 24 waves/CU naturally.
// Grid 1024 = (16 h, 16 qt x 2 half, 2 b): each block owns 1024 keys,
// 16 iters; total staged bytes unchanged. Blocks write unnormalized partial
// O (f32) + row-sums; attn_reduce sums halves and normalizes. Internals =
// round-8 proven kernel. Main loop unrolled x2 (literal cur).
// Numerics: FP32 add reorder only (half-split; key-split passed r6/r8).
// ---------------------------------------------------------------------------
__global__ __launch_bounds__(512, 4)
void attn_mfma(const unsigned short* __restrict__ qmat,
               const unsigned short* __restrict__ kmat,
               const unsigned short* __restrict__ vtg,
               const unsigned char* __restrict__ msk,
               float* __restrict__ opart, float* __restrict__ lspart) {
    const int h = blockIdx.x, yy = blockIdx.y, b = blockIdx.z;
    const int qt = yy >> 1, half = yy & 1;
    const int t = threadIdx.x, w = t >> 6, lane = t & 63;
    const int l15 = lane & 15, quad = lane >> 4;
    const int q0 = qt * 128;

    __shared__ __align__(16) char smem[49152];
    unsigned short* const Ksm = (unsigned short*)smem;            // [2][64*64]
    unsigned short* const Vsm = (unsigned short*)(smem + 16384);  // [2][64*64]
    unsigned short* const Psm = (unsigned short*)(smem + 32768);  // [128*64]

    const size_t bh = (size_t)b * S_ * D_ + (size_t)h * HD_;
    const unsigned short* __restrict__ qp = qmat + bh;
    const unsigned short* __restrict__ kp = kmat + bh + (size_t)half * 1024 * D_;
    const unsigned short* __restrict__ vp = vtg + ((size_t)b * H_ + h) * HD_ * S_ + half * 1024;
    const unsigned char* __restrict__ mb = msk + (size_t)b * S_ * S_ + half * 1024;

    const int rs = lane >> 3, sslot = lane & 7;
    const int sg = (sslot ^ rs) * 8;         // staged global granule col (shorts)
    const int srow = w * 8 + rs;             // staging row 0..63 (8 rows/wave)

    const int qs = w >> 1;                   // q-substrip 0..3 (32 rows each)
    const int kw = (w & 1) * 32;             // wave's key half offset
    const int kst = w & 1;                   // key-half granule base for PV
    const int sw7 = l15 & 7;                 // row swizzle key (all rows &7)

    // Q fragments in registers (loop-invariant): 2 qrow strips x 2 d-halves
    bf16x8 qfr[2][2];
    #pragma unroll
    for (int nt = 0; nt < 2; ++nt)
        #pragma unroll
        for (int dk = 0; dk < 2; ++dk)
            qfr[nt][dk] = *(const bf16x8*)(qp +
                (size_t)(q0 + qs * 32 + nt * 16 + l15) * D_ + dk * 32 + quad * 8);

    f32x4 accO[2][4] = {};
    f32x4 lsA[2] = {};
    bf16x8 ones;
    #pragma unroll
    for (int i = 0; i < 8; ++i) ones[i] = (short)0x3F80;   // bf16 1.0

    // prologue: stage tile 0 into buffer 0 (one 16B DMA per thread per matrix)
    gload_lds16(kp + (size_t)srow * D_ + sg, Ksm + w * 8 * 64);
    gload_lds16(vp + (size_t)srow * S_ + sg, Vsm + w * 8 * 64);

#define ATTN_STEP(IT, CUR)                                                     \
    do {                                                                       \
        const int kt = (IT) * 64;                                              \
        __syncthreads();                                                       \
        unsigned mu[2][2];                                                     \
        _Pragma("unroll")                                                      \
        for (int nt = 0; nt < 2; ++nt) {                                       \
            const unsigned char* __restrict__ mrow =                           \
                mb + (size_t)(q0 + qs * 32 + nt * 16 + l15) * S_ + kt + kw;    \
            mu[nt][0] = *(const unsigned*)(mrow + quad * 4);                   \
            mu[nt][1] = *(const unsigned*)(mrow + 16 + quad * 4);              \
        }                                                                      \
        if ((IT) + 1 < 16) {                                                   \
            const int ktn = kt + 64;                                           \
            gload_lds16(kp + (size_t)(ktn + srow) * D_ + sg,                   \
                        Ksm + ((CUR) ^ 1) * 4096 + w * 8 * 64);                \
            gload_lds16(vp + (size_t)srow * S_ + ktn + sg,                     \
                        Vsm + ((CUR) ^ 1) * 4096 + w * 8 * 64);                \
        }                                                                      \
        f32x4 sc[2][2] = {};                                                   \
        _Pragma("unroll")                                                      \
        for (int dk = 0; dk < 2; ++dk) {                                       \
            bf16x8 kfr[2];                                                     \
            _Pragma("unroll")                                                  \
            for (int mt = 0; mt < 2; ++mt) {                                   \
                const int R = kw + mt * 16 + l15;                              \
                kfr[mt] = *(const bf16x8*)&Ksm[(CUR) * 4096 + R * 64 +         \
                                               (((dk * 4 + quad) ^ sw7) * 8)]; \
            }                                                                  \
            __builtin_amdgcn_s_setprio(1);                                     \
            _Pragma("unroll")                                                  \
            for (int nt = 0; nt < 2; ++nt)                                     \
                _Pragma("unroll")                                              \
                for (int mt = 0; mt < 2; ++mt)                                 \
                    sc[nt][mt] = __builtin_amdgcn_mfma_f32_16x16x32_bf16(      \
                        kfr[mt], qfr[nt][dk], sc[nt][mt], 0, 0, 0);            \
            __builtin_amdgcn_s_setprio(0);                                     \
        }                                                                      \
        _Pragma("unroll")                                                      \
        for (int nt = 0; nt < 2; ++nt) {                                       \
            const int qr = qs * 32 + nt * 16 + l15;                            \
            _Pragma("unroll")                                                  \
            for (int mt = 0; mt < 2; ++mt) {                                   \
                const int mtg = kst * 2 + mt;                                  \
                unsigned p0 = pack2bf(__builtin_amdgcn_exp2f(sc[nt][mt][0]),   \
                                      __builtin_amdgcn_exp2f(sc[nt][mt][1]));  \
                unsigned p1 = pack2bf(__builtin_amdgcn_exp2f(sc[nt][mt][2]),   \
                                      __builtin_amdgcn_exp2f(sc[nt][mt][3]));  \
                const unsigned m0 =                                            \
                    __builtin_amdgcn_perm(0u, mu[nt][mt], 0x01010000u);        \
                const unsigned m1 =                                            \
                    __builtin_amdgcn_perm(0u, mu[nt][mt], 0x03030202u);        \
                p0 = (m0 & 0x3F803F80u) | (~m0 & p0);                          \
                p1 = (m1 & 0x3F803F80u) | (~m1 & p1);                          \
                uint2 pk2; pk2.x = p0; pk2.y = p1;                             \
                *(uint2*)((char*)Psm + qr * 128 +                              \
                          (((2 * mtg + (quad >> 1)) ^ sw7) * 16) +             \
                          (quad & 1) * 8) = pk2;                               \
            }                                                                  \
        }                                                                      \
        {                                                                      \
            bf16x8 vfr[4];                                                     \
            _Pragma("unroll")                                                  \
            for (int dt = 0; dt < 4; ++dt) {                                   \
                const int R = dt * 16 + l15;                                   \
                vfr[dt] = *(const bf16x8*)&Vsm[(CUR) * 4096 + R * 64 +         \
                                               (((kst * 4 + quad) ^ sw7) * 8)];\
            }                                                                  \
            _Pragma("unroll")                                                  \
            for (int nt = 0; nt < 2; ++nt) {                                   \
                const int qr = qs * 32 + nt * 16 + l15;                        \
                bf16x8 pfr = *(const bf16x8*)((const char*)Psm + qr * 128 +    \
                                              (((kst * 4 + quad) ^ sw7) * 16));\
                __builtin_amdgcn_s_setprio(1);                                 \
                _Pragma("unroll")                                              \
                for (int dt = 0; dt < 4; ++dt)                                 \
                    accO[nt][dt] = __builtin_amdgcn_mfma_f32_16x16x32_bf16(    \
                        pfr, vfr[dt], accO[nt][dt], 0, 0, 0);                  \
                lsA[nt] = __builtin_amdgcn_mfma_f32_16x16x32_bf16(             \
                    pfr, ones, lsA[nt], 0, 0, 0);                              \
                __builtin_amdgcn_s_setprio(0);                                 \
            }                                                                  \
        }                                                                      \
    } while (0)

    for (int io = 0; io < 8; ++io) {
        ATTN_STEP(2 * io, 0);
        ATTN_STEP(2 * io + 1, 1);
    }
#undef ATTN_STEP

    // pair reduction: odd wave's partial accO/lsA -> even wave via smem
    // (Ks/Vs/Ps dead; 8 strips x 64 lanes x 20 floats = 40960B <= 49152B)
    __syncthreads();
    float* const Red = (float*)smem;
    if (w & 1) {
        #pragma unroll
        for (int nt = 0; nt < 2; ++nt) {
            const int pidx = ((qs * 2 + nt) * 64 + lane) * 20;
            #pragma unroll
            for (int dt = 0; dt < 4; ++dt)
                *(f32x4*)&Red[pidx + dt * 4] = accO[nt][dt];
            *(f32x4*)&Red[pidx + 16] = lsA[nt];
        }
    }
    __syncthreads();
    if (!(w & 1)) {
        float* __restrict__ op = opart +
            (((size_t)half * B_ + b) * S_ + q0) * D_ + (size_t)h * HD_;
        #pragma unroll
        for (int nt = 0; nt < 2; ++nt) {
            const int pidx = ((qs * 2 + nt) * 64 + lane) * 20;
            #pragma unroll
            for (int dt = 0; dt < 4; ++dt)
                accO[nt][dt] += *(const f32x4*)&Red[pidx + dt * 4];
            lsA[nt] += *(const f32x4*)&Red[pidx + 16];

            #pragma unroll
            for (int r = 0; r < 4; ++r) {
                const int row = qs * 32 + nt * 16 + quad * 4 + r;
                #pragma unroll
                for (int dt = 0; dt < 4; ++dt)
                    op[(size_t)row * D_ + dt * 16 + l15] = accO[nt][dt][r];
            }
            if (l15 == 0) {
                #pragma unroll
                for (int r = 0; r < 4; ++r) {
                    const int row = qs * 32 + nt * 16 + quad * 4 + r;
                    lspart[(((size_t)half * B_ + b) * H_ + h) * S_ + q0 + row] =
                        lsA[nt][r];
                }
            }
        }
    }
}

// ---------------------------------------------------------------------------
// Reduce: out = (Op[0]+Op[1]) / (Ls[0]+Ls[1]). 4M f32, float4/thread.
// ---------------------------------------------------------------------------
__global__ __launch_bounds__(256)
void attn_reduce(const float* __restrict__ Op, const float* __restrict__ Ls,
                 float* __restrict__ out) {
    const size_t i = ((size_t)blockIdx.x * 256 + threadIdx.x) * 4;
    const size_t HALF = (size_t)B_ * S_ * D_;   // 4M floats
    float4 p0 = *(const float4*)(Op + i);
    float4 p1 = *(const float4*)(Op + HALF + i);
    const int rowg = (int)(i >> 10);            // b*S + row
    const int col = (int)(i & 1023);
    const int b = rowg >> 11, row = rowg & 2047, h = col >> 6;
    const float l = Ls[((size_t)b * H_ + h) * S_ + row] +
                    Ls[((size_t)(B_ + b) * H_ + h) * S_ + row];
    const float inv = 1.0f / l;
    float4 o;
    o.x = (p0.x + p1.x) * inv;
    o.y = (p0.y + p1.y) * inv;
    o.z = (p0.z + p1.z) * inv;
    o.w = (p0.w + p1.w) * inv;
    *(float4*)(out + i) = o;
}

extern "C" void kernel_launch(void* const* d_in, const int* in_sizes, int n_in,
                              void* d_out, int out_size, void* d_ws, size_t ws_size,
                              hipStream_t stream) {
    (void)in_sizes; (void)n_in; (void)out_size; (void)ws_size;
    const float* x    = (const float*)d_in[0];
    const int*   mask = (const int*)d_in[1];
    const float* Wq   = (const float*)d_in[2];
    const float* bq   = (const float*)d_in[3];
    const float* Wk   = (const float*)d_in[4];
    const float* bk   = (const float*)d_in[5];
    const float* Wv   = (const float*)d_in[6];
    const float* bv   = (const float*)d_in[7];
    float* out = (float*)d_out;

    const size_t M1 = (size_t)1024 * 1024;
    unsigned short* xb  = (unsigned short*)d_ws;      // 4M bf16
    unsigned short* wtb = xb + 4 * M1;                // 3M bf16
    unsigned short* qb  = wtb + 3 * M1;               // 4M bf16
    unsigned short* kb  = qb + 4 * M1;                // 4M bf16
    unsigned short* vtb = kb + 4 * M1;                // 4M bf16 (transposed V)
    unsigned char*  mk  = (unsigned char*)(vtb + 4 * M1);  // 8M u8 (0xFF/0x00)
    float* opart = (float*)(mk + 8 * M1);             // 2 x B*S*D f32 = 32MB
    float* lspart = opart + 2 * (size_t)B_ * S_ * D_; // 2 x B*H*S f32 = 512KB

    prep<<<4864, 256, 0, stream>>>(x, xb, mask, mk, Wq, Wk, Wv, wtb);
    qkv_gemm<<<dim3(24, 32), 512, 0, stream>>>(xb, wtb, bq, bk, bv, qb, kb, vtb);
    attn_mfma<<<dim3(16, 32, 2), 512, 0, stream>>>(qb, kb, vtb, mk, opart, lspart);
    attn_reduce<<<4096, 256, 0, stream>>>(opart, lspart, out);
}

// Round 11
// 216.667 us; speedup vs baseline: 2.3908x; 1.0913x over previous
//
#include <hip/hip_runtime.h>
#include <cstdint>
#include <cstddef>

static constexpr int B_ = 2, S_ = 2048, D_ = 1024, H_ = 16, HD_ = 64;

typedef float f32x4 __attribute__((ext_vector_type(4)));
typedef short bf16x8 __attribute__((ext_vector_type(8)));

__device__ __forceinline__ unsigned short f2bf(float f) {
    union { float f; unsigned int u; } v; v.f = f;
    unsigned int r = v.u + 0x7FFFu + ((v.u >> 16) & 1u);   // RNE
    return (unsigned short)(r >> 16);
}

// 5-op RNE pair pack. Bit-identical to f2bf(a) | f2bf(b)<<16. NO hardware
// cvt_pk (round-2 failure: v_cvt_pk_bf16_f32 is not RNE-equivalent).
__device__ __forceinline__ unsigned pack2bf(float a, float b) {
    union { float f; unsigned u; } va, vb; va.f = a; vb.f = b;
    unsigned ra = va.u + 0x7FFFu + ((va.u >> 16) & 1u);
    unsigned rb = vb.u + 0x7FFFu + ((vb.u >> 16) & 1u);
    return __builtin_amdgcn_perm(rb, ra, 0x07060302u);
}

// async global->LDS, 16B per lane. LDS dest = wave-uniform base + lane*16.
__device__ __forceinline__ void gload_lds16(const void* g, void* l) {
    __builtin_amdgcn_global_load_lds(
        (const __attribute__((address_space(1))) void*)g,
        (__attribute__((address_space(3))) void*)l, 16, 0, 0);
}

// ---------------------------------------------------------------------------
// Fused prep: [0,2048) cast x->bf16 | [2048,4096) mask int32->u8 (0xFF/0x00) |
// [4096,4864) W transpose+cast. (unchanged, proven)
// ---------------------------------------------------------------------------
__global__ __launch_bounds__(256)
void prep(const float* __restrict__ x, unsigned short* __restrict__ xo,
          const int* __restrict__ m, unsigned char* __restrict__ mo,
          const float* __restrict__ Wq, const float* __restrict__ Wk,
          const float* __restrict__ Wv, unsigned short* __restrict__ wt) {
    __shared__ unsigned short Ts[64][72];
    const int bid = blockIdx.x, t = threadIdx.x;
    if (bid < 2048) {
        size_t i = ((size_t)bid * 256 + t) * 8;
        float4 a = *(const float4*)(x + i);
        float4 c = *(const float4*)(x + i + 4);
        uint4 r;
        r.x = pack2bf(a.x, a.y); r.y = pack2bf(a.z, a.w);
        r.z = pack2bf(c.x, c.y); r.w = pack2bf(c.z, c.w);
        *(uint4*)(xo + i) = r;
    } else if (bid < 4096) {
        size_t i = ((size_t)(bid - 2048) * 256 + t) * 16;
        uint4 r;
        unsigned w[4];
        #pragma unroll
        for (int g = 0; g < 4; ++g) {
            int4 v = *(const int4*)(m + i + g * 4);
            w[g] = (v.x ? 0xFFu : 0u) | (v.y ? 0xFF00u : 0u) |
                   (v.z ? 0xFF0000u : 0u) | (v.w ? 0xFF000000u : 0u);
        }
        r.x = w[0]; r.y = w[1]; r.z = w[2]; r.w = w[3];
        *(uint4*)(mo + i) = r;
    } else {
        const int tid = bid - 4096;            // 0..767
        const int mat = tid >> 8, tile = tid & 255;
        const float* __restrict__ W = (mat == 0) ? Wq : (mat == 1) ? Wk : Wv;
        unsigned short* __restrict__ o = wt + (size_t)mat * D_ * D_;
        const int n0 = (tile & 15) * 64, k0 = (tile >> 4) * 64;
        {
            const int nl = t & 63, kb = t >> 6;
            #pragma unroll
            for (int i = 0; i < 16; ++i) {
                int k = kb + i * 4;
                Ts[nl][k] = f2bf(W[(size_t)(k0 + k) * D_ + n0 + nl]);
            }
        }
        __syncthreads();
        {
            const int kl = t & 63, nb = t >> 6;
            #pragma unroll
            for (int i = 0; i < 16; ++i) {
                int n = nb + i * 4;
                o[(size_t)(n0 + n) * D_ + k0 + kl] = Ts[n][kl];
            }
        }
    }
}

// ---------------------------------------------------------------------------
// QKV GEMM, bf16 MFMA 16x16x32. 128x128 tile, BK=32, double-buffered DMA.
// 512 threads (8 waves, wave-tile 64x32), 24 waves/CU. (round-5, proven)
// ---------------------------------------------------------------------------
__global__ __launch_bounds__(512)
void qkv_gemm(const unsigned short* __restrict__ xb, const unsigned short* __restrict__ wt,
              const float* __restrict__ bq, const float* __restrict__ bk,
              const float* __restrict__ bv,
              unsigned short* __restrict__ qo, unsigned short* __restrict__ ko,
              unsigned short* __restrict__ vto) {
    const int bx = blockIdx.x;            // 0..23: mat*8 + ntile
    const int by = blockIdx.y;            // 0..31: mtile
    const int mat = bx >> 3;
    const int ncol0 = (bx & 7) * 128;
    const float* __restrict__ bias = (mat == 0) ? bq : (mat == 1) ? bk : bv;
    const unsigned short* __restrict__ Wm = wt + (size_t)mat * D_ * D_;

    __shared__ unsigned short As[2][128 * 32];
    __shared__ unsigned short Bs[2][128 * 32];

    const int t = threadIdx.x;
    const int w = t >> 6, lane = t & 63;
    const int l15 = lane & 15, quad = lane >> 4;
    const int mw = (w >> 2) * 64, nw = (w & 3) * 32;   // wave tile 64x32
    const int rowBase = by * 128;

    const int r16 = lane >> 2;                       // 0..15
    const int sslot = lane & 3;
    const int sg = (sslot ^ ((r16 >> 1) & 3)) * 8;   // staged global col (shorts)
    const int srow = w * 16 + r16;                   // staging row 0..127
    const int rcol = (quad ^ ((l15 >> 1) & 3)) * 8;  // fragment read col (shorts)

    f32x4 acc[4][2] = {};

    gload_lds16(xb + (size_t)(rowBase + srow) * D_ + sg, &As[0][w * 16 * 32]);
    gload_lds16(Wm + (size_t)(ncol0 + srow) * D_ + sg, &Bs[0][w * 16 * 32]);

    for (int it = 0; it < 32; ++it) {
        const int cur = it & 1;
        __syncthreads();
        if (it + 1 < 32) {
            const int ktn = (it + 1) * 32;
            gload_lds16(xb + (size_t)(rowBase + srow) * D_ + ktn + sg,
                        &As[cur ^ 1][w * 16 * 32]);
            gload_lds16(Wm + (size_t)(ncol0 + srow) * D_ + ktn + sg,
                        &Bs[cur ^ 1][w * 16 * 32]);
        }

        bf16x8 a[4], b[2];
        #pragma unroll
        for (int i = 0; i < 4; ++i)
            a[i] = *(const bf16x8*)&As[cur][(mw + i * 16 + l15) * 32 + rcol];
        #pragma unroll
        for (int j = 0; j < 2; ++j)
            b[j] = *(const bf16x8*)&Bs[cur][(nw + j * 16 + l15) * 32 + rcol];
        #pragma unroll
        for (int i = 0; i < 4; ++i)
            #pragma unroll
            for (int j = 0; j < 2; ++j)
                acc[i][j] = __builtin_amdgcn_mfma_f32_16x16x32_bf16(a[i], b[j], acc[i][j], 0, 0, 0);
    }

    if (mat < 2) {
        unsigned short* __restrict__ O = (mat == 0) ? qo : ko;
        const float osc = (mat == 0) ? 0.18033688011112443f : 1.0f;  // 0.125*log2(e)
        #pragma unroll
        for (int j = 0; j < 2; ++j) {
            const int col = ncol0 + nw + j * 16 + l15;
            const float bb = bias[col];
            #pragma unroll
            for (int i = 0; i < 4; ++i)
                #pragma unroll
                for (int r = 0; r < 4; ++r) {
                    const int m = rowBase + mw + i * 16 + quad * 4 + r;
                    O[(size_t)m * D_ + col] = f2bf((acc[i][j][r] + bb) * osc);
                }
        }
    } else {
        #pragma unroll
        for (int j = 0; j < 2; ++j) {
            const int col = ncol0 + nw + j * 16 + l15;
            const float bb = bias[col];
            const int hh = col >> 6, hd = col & 63;
            #pragma unroll
            for (int i = 0; i < 4; ++i) {
                const int m0 = rowBase + mw + i * 16 + quad * 4;
                const int bg = m0 >> 11, s0 = m0 & 2047;
                ushort4 pk;
                pk.x = f2bf(acc[i][j][0] + bb);
                pk.y = f2bf(acc[i][j][1] + bb);
                pk.z = f2bf(acc[i][j][2] + bb);
                pk.w = f2bf(acc[i][j][3] + bb);
                *(ushort4*)&vto[(((size_t)bg * H_ + hh) * HD_ + hd) * S_ + s0] = pk;
            }
        }
    }
}

// ---------------------------------------------------------------------------
// Flash attention — round-8 structure (best measured: 80.8us, VGPR 60) +
// T4 counted-vmcnt pipeline (m218: counted-vs-drain0 was the big GEMM lever):
//   * TRIPLE-buffered K/V (3 x 8KB each), prefetch distance 2: tile i+2 is
//     issued during iter i, so 2 tiles (4 DMAs) stay in flight ACROSS the
//     barrier instead of being drained every iter by __syncthreads' vmcnt(0).
//   * Barrier = ONE fused volatile asm "s_waitcnt vmcnt(N); s_barrier" with
//     memory clobber (no ds_read can be hoisted between wait and barrier —
//     rule-18 hazard class). In-order vmcnt semantics (m135): N = #loads
//     issued after the tile being consumed. Per-wave issue order:
//     [qfr(4)] K0 V0 K1 V1 | m0(4) K2 V2 | m1 K3 V3 | ... | m29 K31 V31 |
//     m30 | m31  =>  step0: N=2, steps1..30: N=6, step31: N=4.
//   * Writer/reader disjointness: DMA at iter i targets buf (i+2)%3; its
//     last readers were iter i-1, all past barrier i before the issue.
// Key-half grid split REVERTED (r10: straggler tail + halved amortization,
// attn 110us). Numerics bit-identical to r8 (pure scheduling change).
// LDS 64KB (3x8 K + 3x8 V + 16 Ps) -> 2 blocks/CU (grid caps there anyway).
// launch_bounds(512,4): cap 128 >> ~70 need (r6/r9 spill lessons).
// ---------------------------------------------------------------------------
__global__ __launch_bounds__(512, 4)
void attn_mfma(const unsigned short* __restrict__ qmat,
               const unsigned short* __restrict__ kmat,
               const unsigned short* __restrict__ vtg,
               const unsigned char* __restrict__ msk, float* __restrict__ out) {
    const int h = blockIdx.x, qt = blockIdx.y, b = blockIdx.z;
    const int t = threadIdx.x, w = t >> 6, lane = t & 63;
    const int l15 = lane & 15, quad = lane >> 4;
    const int q0 = qt * 128;

    __shared__ __align__(16) char smem[65536];
    unsigned short* const Ksm = (unsigned short*)smem;            // [3][64*64]
    unsigned short* const Vsm = (unsigned short*)(smem + 24576);  // [3][64*64]
    unsigned short* const Psm = (unsigned short*)(smem + 49152);  // [128*64]

    const size_t bh = (size_t)b * S_ * D_ + (size_t)h * HD_;
    const unsigned short* __restrict__ qp = qmat + bh;
    const unsigned short* __restrict__ kp = kmat + bh;
    const unsigned short* __restrict__ vp = vtg + ((size_t)b * H_ + h) * HD_ * S_;
    const unsigned char* __restrict__ mb = msk + (size_t)b * S_ * S_;

    const int rs = lane >> 3, sslot = lane & 7;
    const int sg = (sslot ^ rs) * 8;         // staged global granule col (shorts)
    const int srow = w * 8 + rs;             // staging row 0..63 (8 rows/wave)

    const int qs = w >> 1;                   // q-substrip 0..3 (32 rows each)
    const int kw = (w & 1) * 32;             // wave's key half offset
    const int kst = w & 1;                   // key-half granule base for PV
    const int sw7 = l15 & 7;                 // row swizzle key (all rows &7)

    // Q fragments in registers (loop-invariant): 2 qrow strips x 2 d-halves
    bf16x8 qfr[2][2];
    #pragma unroll
    for (int nt = 0; nt < 2; ++nt)
        #pragma unroll
        for (int dk = 0; dk < 2; ++dk)
            qfr[nt][dk] = *(const bf16x8*)(qp +
                (size_t)(q0 + qs * 32 + nt * 16 + l15) * D_ + dk * 32 + quad * 8);

    f32x4 accO[2][4] = {};
    f32x4 lsA[2] = {};
    bf16x8 ones;
    #pragma unroll
    for (int i = 0; i < 8; ++i) ones[i] = (short)0x3F80;   // bf16 1.0

    // prologue: stage tiles 0 and 1 into bufs 0,1 (issue order K0 V0 K1 V1)
    gload_lds16(kp + (size_t)srow * D_ + sg, Ksm + w * 8 * 64);
    gload_lds16(vp + (size_t)srow * S_ + sg, Vsm + w * 8 * 64);
    gload_lds16(kp + (size_t)(64 + srow) * D_ + sg, Ksm + 4096 + w * 8 * 64);
    gload_lds16(vp + (size_t)srow * S_ + 64 + sg, Vsm + 4096 + w * 8 * 64);

#define ATTN_STEP(IT, BUF, PRE, WAITN, DOPRE)                                  \
    do {                                                                       \
        const int kt = (IT) * 64;                                              \
        asm volatile("s_waitcnt vmcnt(%0)\n\ts_barrier"                        \
                     :: "n"(WAITN) : "memory");                                \
        unsigned mu[2][2];                                                     \
        _Pragma("unroll")                                                      \
        for (int nt = 0; nt < 2; ++nt) {                                       \
            const unsigned char* __restrict__ mrow =                           \
                mb + (size_t)(q0 + qs * 32 + nt * 16 + l15) * S_ + kt + kw;    \
            mu[nt][0] = *(const unsigned*)(mrow + quad * 4);                   \
            mu[nt][1] = *(const unsigned*)(mrow + 16 + quad * 4);              \
        }                                                                      \
        if (DOPRE) {                                                           \
            const int ktn = kt + 128;                                          \
            gload_lds16(kp + (size_t)(ktn + srow) * D_ + sg,                   \
                        Ksm + (PRE) * 4096 + w * 8 * 64);                      \
            gload_lds16(vp + (size_t)srow * S_ + ktn + sg,                     \
                        Vsm + (PRE) * 4096 + w * 8 * 64);                      \
        }                                                                      \
        f32x4 sc[2][2] = {};                                                   \
        _Pragma("unroll")                                                      \
        for (int dk = 0; dk < 2; ++dk) {                                       \
            bf16x8 kfr[2];                                                     \
            _Pragma("unroll")                                                  \
            for (int mt = 0; mt < 2; ++mt) {                                   \
                const int R = kw + mt * 16 + l15;                              \
                kfr[mt] = *(const bf16x8*)&Ksm[(BUF) * 4096 + R * 64 +         \
                                               (((dk * 4 + quad) ^ sw7) * 8)]; \
            }                                                                  \
            __builtin_amdgcn_s_setprio(1);                                     \
            _Pragma("unroll")                                                  \
            for (int nt = 0; nt < 2; ++nt)                                     \
                _Pragma("unroll")                                              \
                for (int mt = 0; mt < 2; ++mt)                                 \
                    sc[nt][mt] = __builtin_amdgcn_mfma_f32_16x16x32_bf16(      \
                        kfr[mt], qfr[nt][dk], sc[nt][mt], 0, 0, 0);            \
            __builtin_amdgcn_s_setprio(0);                                     \
        }                                                                      \
        _Pragma("unroll")                                                      \
        for (int nt = 0; nt < 2; ++nt) {                                       \
            const int qr = qs * 32 + nt * 16 + l15;                            \
            _Pragma("unroll")                                                  \
            for (int mt = 0; mt < 2; ++mt) {                                   \
                const int mtg = kst * 2 + mt;                                  \
                unsigned p0 = pack2bf(__builtin_amdgcn_exp2f(sc[nt][mt][0]),   \
                                      __builtin_amdgcn_exp2f(sc[nt][mt][1]));  \
                unsigned p1 = pack2bf(__builtin_amdgcn_exp2f(sc[nt][mt][2]),   \
                                      __builtin_amdgcn_exp2f(sc[nt][mt][3]));  \
                const unsigned m0 =                                            \
                    __builtin_amdgcn_perm(0u, mu[nt][mt], 0x01010000u);        \
                const unsigned m1 =                                            \
                    __builtin_amdgcn_perm(0u, mu[nt][mt], 0x03030202u);        \
                p0 = (m0 & 0x3F803F80u) | (~m0 & p0);                          \
                p1 = (m1 & 0x3F803F80u) | (~m1 & p1);                          \
                uint2 pk2; pk2.x = p0; pk2.y = p1;                             \
                *(uint2*)((char*)Psm + qr * 128 +                              \
                          (((2 * mtg + (quad >> 1)) ^ sw7) * 16) +             \
                          (quad & 1) * 8) = pk2;                               \
            }                                                                  \
        }                                                                      \
        {                                                                      \
            bf16x8 vfr[4];                                                     \
            _Pragma("unroll")                                                  \
            for (int dt = 0; dt < 4; ++dt) {                                   \
                const int R = dt * 16 + l15;                                   \
                vfr[dt] = *(const bf16x8*)&Vsm[(BUF) * 4096 + R * 64 +         \
                                               (((kst * 4 + quad) ^ sw7) * 8)];\
            }                                                                  \
            _Pragma("unroll")                                                  \
            for (int nt = 0; nt < 2; ++nt) {                                   \
                const int qr = qs * 32 + nt * 16 + l15;                        \
                bf16x8 pfr = *(const bf16x8*)((const char*)Psm + qr * 128 +    \
                                              (((kst * 4 + quad) ^ sw7) * 16));\
                __builtin_amdgcn_s_setprio(1);                                 \
                _Pragma("unroll")                                              \
                for (int dt = 0; dt < 4; ++dt)                                 \
                    accO[nt][dt] = __builtin_amdgcn_mfma_f32_16x16x32_bf16(    \
                        pfr, vfr[dt], accO[nt][dt], 0, 0, 0);                  \
                lsA[nt] = __builtin_amdgcn_mfma_f32_16x16x32_bf16(             \
                    pfr, ones, lsA[nt], 0, 0, 0);                              \
                __builtin_amdgcn_s_setprio(0);                                 \
            }                                                                  \
        }                                                                      \
    } while (0)

    // steps 0..2 (pipeline fill), 3..29 (steady), 30..31 (drain)
    ATTN_STEP(0, 0, 2, 2, true);
    ATTN_STEP(1, 1, 0, 6, true);
    ATTN_STEP(2, 2, 1, 6, true);
    for (int io = 1; io < 10; ++io) {
        ATTN_STEP(3 * io + 0, 0, 2, 6, true);
        ATTN_STEP(3 * io + 1, 1, 0, 6, true);
        ATTN_STEP(3 * io + 2, 2, 1, 6, true);
    }
    ATTN_STEP(30, 0, 2, 6, false);
    ATTN_STEP(31, 1, 0, 4, false);
#undef ATTN_STEP

    // pair reduction: odd wave's partial accO/lsA -> even wave via smem
    // (Ks/Vs/Ps dead; 8 strips x 64 lanes x 20 floats = 40960B <= 65536B)
    __syncthreads();
    float* const Red = (float*)smem;
    if (w & 1) {
        #pragma unroll
        for (int nt = 0; nt < 2; ++nt) {
            const int pidx = ((qs * 2 + nt) * 64 + lane) * 20;
            #pragma unroll
            for (int dt = 0; dt < 4; ++dt)
                *(f32x4*)&Red[pidx + dt * 4] = accO[nt][dt];
            *(f32x4*)&Red[pidx + 16] = lsA[nt];
        }
    }
    __syncthreads();
    if (!(w & 1)) {
        float* __restrict__ ob = out + ((size_t)b * S_ + q0) * D_ + (size_t)h * HD_;
        #pragma unroll
        for (int nt = 0; nt < 2; ++nt) {
            const int pidx = ((qs * 2 + nt) * 64 + lane) * 20;
            #pragma unroll
            for (int dt = 0; dt < 4; ++dt)
                accO[nt][dt] += *(const f32x4*)&Red[pidx + dt * 4];
            lsA[nt] += *(const f32x4*)&Red[pidx + 16];

            #pragma unroll
            for (int r = 0; r < 4; ++r) {
                const float inv = 1.0f / lsA[nt][r];
                const int row = qs * 32 + nt * 16 + quad * 4 + r;
                #pragma unroll
                for (int dt = 0; dt < 4; ++dt)
                    ob[(size_t)row * D_ + dt * 16 + l15] = accO[nt][dt][r] * inv;
            }
        }
    }
}

extern "C" void kernel_launch(void* const* d_in, const int* in_sizes, int n_in,
                              void* d_out, int out_size, void* d_ws, size_t ws_size,
                              hipStream_t stream) {
    (void)in_sizes; (void)n_in; (void)out_size; (void)ws_size;
    const float* x    = (const float*)d_in[0];
    const int*   mask = (const int*)d_in[1];
    const float* Wq   = (const float*)d_in[2];
    const float* bq   = (const float*)d_in[3];
    const float* Wk   = (const float*)d_in[4];
    const float* bk   = (const float*)d_in[5];
    const float* Wv   = (const float*)d_in[6];
    const float* bv   = (const float*)d_in[7];
    float* out = (float*)d_out;

    const size_t M1 = (size_t)1024 * 1024;
    unsigned short* xb  = (unsigned short*)d_ws;      // 4M bf16
    unsigned short* wtb = xb + 4 * M1;                // 3M bf16
    unsigned short* qb  = wtb + 3 * M1;               // 4M bf16
    unsigned short* kb  = qb + 4 * M1;                // 4M bf16
    unsigned short* vtb = kb + 4 * M1;                // 4M bf16 (transposed V)
    unsigned char*  mk  = (unsigned char*)(vtb + 4 * M1);  // 8M u8 (0xFF/0x00)

    prep<<<4864, 256, 0, stream>>>(x, xb, mask, mk, Wq, Wk, Wv, wtb);
    qkv_gemm<<<dim3(24, 32), 512, 0, stream>>>(xb, wtb, bq, bk, bv, qb, kb, vtb);
    attn_mfma<<<dim3(16, 16, 2), 512, 0, stream>>>(qb, kb, vtb, mk, out);
}

// Round 12
// 212.819 us; speedup vs baseline: 2.4341x; 1.0181x over previous
//
#include <hip/hip_runtime.h>
#include <cstdint>
#include <cstddef>

static constexpr int B_ = 2, S_ = 2048, D_ = 1024, H_ = 16, HD_ = 64;

typedef float f32x4 __attribute__((ext_vector_type(4)));
typedef short bf16x8 __attribute__((ext_vector_type(8)));

__device__ __forceinline__ unsigned short f2bf(float f) {
    union { float f; unsigned int u; } v; v.f = f;
    unsigned int r = v.u + 0x7FFFu + ((v.u >> 16) & 1u);   // RNE
    return (unsigned short)(r >> 16);
}

// 5-op RNE pair pack. Bit-identical to f2bf(a) | f2bf(b)<<16. NO hardware
// cvt_pk (round-2 failure: v_cvt_pk_bf16_f32 is not RNE-equivalent).
__device__ __forceinline__ unsigned pack2bf(float a, float b) {
    union { float f; unsigned u; } va, vb; va.f = a; vb.f = b;
    unsigned ra = va.u + 0x7FFFu + ((va.u >> 16) & 1u);
    unsigned rb = vb.u + 0x7FFFu + ((vb.u >> 16) & 1u);
    return __builtin_amdgcn_perm(rb, ra, 0x07060302u);
}

// async global->LDS, 16B per lane. LDS dest = wave-uniform base + lane*16.
__device__ __forceinline__ void gload_lds16(const void* g, void* l) {
    __builtin_amdgcn_global_load_lds(
        (const __attribute__((address_space(1))) void*)g,
        (__attribute__((address_space(3))) void*)l, 16, 0, 0);
}

// ---------------------------------------------------------------------------
// Fused prep: [0,2048) cast x->bf16 | [2048,4096) mask int32->u8 (0xFF/0x00) |
// [4096,4864) W transpose+cast. (unchanged, proven)
// ---------------------------------------------------------------------------
__global__ __launch_bounds__(256)
void prep(const float* __restrict__ x, unsigned short* __restrict__ xo,
          const int* __restrict__ m, unsigned char* __restrict__ mo,
          const float* __restrict__ Wq, const float* __restrict__ Wk,
          const float* __restrict__ Wv, unsigned short* __restrict__ wt) {
    __shared__ unsigned short Ts[64][72];
    const int bid = blockIdx.x, t = threadIdx.x;
    if (bid < 2048) {
        size_t i = ((size_t)bid * 256 + t) * 8;
        float4 a = *(const float4*)(x + i);
        float4 c = *(const float4*)(x + i + 4);
        uint4 r;
        r.x = pack2bf(a.x, a.y); r.y = pack2bf(a.z, a.w);
        r.z = pack2bf(c.x, c.y); r.w = pack2bf(c.z, c.w);
        *(uint4*)(xo + i) = r;
    } else if (bid < 4096) {
        size_t i = ((size_t)(bid - 2048) * 256 + t) * 16;
        uint4 r;
        unsigned w[4];
        #pragma unroll
        for (int g = 0; g < 4; ++g) {
            int4 v = *(const int4*)(m + i + g * 4);
            w[g] = (v.x ? 0xFFu : 0u) | (v.y ? 0xFF00u : 0u) |
                   (v.z ? 0xFF0000u : 0u) | (v.w ? 0xFF000000u : 0u);
        }
        r.x = w[0]; r.y = w[1]; r.z = w[2]; r.w = w[3];
        *(uint4*)(mo + i) = r;
    } else {
        const int tid = bid - 4096;            // 0..767
        const int mat = tid >> 8, tile = tid & 255;
        const float* __restrict__ W = (mat == 0) ? Wq : (mat == 1) ? Wk : Wv;
        unsigned short* __restrict__ o = wt + (size_t)mat * D_ * D_;
        const int n0 = (tile & 15) * 64, k0 = (tile >> 4) * 64;
        {
            const int nl = t & 63, kb = t >> 6;
            #pragma unroll
            for (int i = 0; i < 16; ++i) {
                int k = kb + i * 4;
                Ts[nl][k] = f2bf(W[(size_t)(k0 + k) * D_ + n0 + nl]);
            }
        }
        __syncthreads();
        {
            const int kl = t & 63, nb = t >> 6;
            #pragma unroll
            for (int i = 0; i < 16; ++i) {
                int n = nb + i * 4;
                o[(size_t)(n0 + n) * D_ + k0 + kl] = Ts[n][kl];
            }
        }
    }
}

// ---------------------------------------------------------------------------
// QKV GEMM, bf16 MFMA 16x16x32. 128x128 tile, BK=32, double-buffered DMA.
// 512 threads (8 waves, wave-tile 64x32), 24 waves/CU. (round-5, proven)
// ---------------------------------------------------------------------------
__global__ __launch_bounds__(512)
void qkv_gemm(const unsigned short* __restrict__ xb, const unsigned short* __restrict__ wt,
              const float* __restrict__ bq, const float* __restrict__ bk,
              const float* __restrict__ bv,
              unsigned short* __restrict__ qo, unsigned short* __restrict__ ko,
              unsigned short* __restrict__ vto) {
    const int bx = blockIdx.x;            // 0..23: mat*8 + ntile
    const int by = blockIdx.y;            // 0..31: mtile
    const int mat = bx >> 3;
    const int ncol0 = (bx & 7) * 128;
    const float* __restrict__ bias = (mat == 0) ? bq : (mat == 1) ? bk : bv;
    const unsigned short* __restrict__ Wm = wt + (size_t)mat * D_ * D_;

    __shared__ unsigned short As[2][128 * 32];
    __shared__ unsigned short Bs[2][128 * 32];

    const int t = threadIdx.x;
    const int w = t >> 6, lane = t & 63;
    const int l15 = lane & 15, quad = lane >> 4;
    const int mw = (w >> 2) * 64, nw = (w & 3) * 32;   // wave tile 64x32
    const int rowBase = by * 128;

    const int r16 = lane >> 2;                       // 0..15
    const int sslot = lane & 3;
    const int sg = (sslot ^ ((r16 >> 1) & 3)) * 8;   // staged global col (shorts)
    const int srow = w * 16 + r16;                   // staging row 0..127
    const int rcol = (quad ^ ((l15 >> 1) & 3)) * 8;  // fragment read col (shorts)

    f32x4 acc[4][2] = {};

    gload_lds16(xb + (size_t)(rowBase + srow) * D_ + sg, &As[0][w * 16 * 32]);
    gload_lds16(Wm + (size_t)(ncol0 + srow) * D_ + sg, &Bs[0][w * 16 * 32]);

    for (int it = 0; it < 32; ++it) {
        const int cur = it & 1;
        __syncthreads();
        if (it + 1 < 32) {
            const int ktn = (it + 1) * 32;
            gload_lds16(xb + (size_t)(rowBase + srow) * D_ + ktn + sg,
                        &As[cur ^ 1][w * 16 * 32]);
            gload_lds16(Wm + (size_t)(ncol0 + srow) * D_ + ktn + sg,
                        &Bs[cur ^ 1][w * 16 * 32]);
        }

        bf16x8 a[4], b[2];
        #pragma unroll
        for (int i = 0; i < 4; ++i)
            a[i] = *(const bf16x8*)&As[cur][(mw + i * 16 + l15) * 32 + rcol];
        #pragma unroll
        for (int j = 0; j < 2; ++j)
            b[j] = *(const bf16x8*)&Bs[cur][(nw + j * 16 + l15) * 32 + rcol];
        #pragma unroll
        for (int i = 0; i < 4; ++i)
            #pragma unroll
            for (int j = 0; j < 2; ++j)
                acc[i][j] = __builtin_amdgcn_mfma_f32_16x16x32_bf16(a[i], b[j], acc[i][j], 0, 0, 0);
    }

    if (mat < 2) {
        unsigned short* __restrict__ O = (mat == 0) ? qo : ko;
        const float osc = (mat == 0) ? 0.18033688011112443f : 1.0f;  // 0.125*log2(e)
        #pragma unroll
        for (int j = 0; j < 2; ++j) {
            const int col = ncol0 + nw + j * 16 + l15;
            const float bb = bias[col];
            #pragma unroll
            for (int i = 0; i < 4; ++i)
                #pragma unroll
                for (int r = 0; r < 4; ++r) {
                    const int m = rowBase + mw + i * 16 + quad * 4 + r;
                    O[(size_t)m * D_ + col] = f2bf((acc[i][j][r] + bb) * osc);
                }
        }
    } else {
        #pragma unroll
        for (int j = 0; j < 2; ++j) {
            const int col = ncol0 + nw + j * 16 + l15;
            const float bb = bias[col];
            const int hh = col >> 6, hd = col & 63;
            #pragma unroll
            for (int i = 0; i < 4; ++i) {
                const int m0 = rowBase + mw + i * 16 + quad * 4;
                const int bg = m0 >> 11, s0 = m0 & 2047;
                ushort4 pk;
                pk.x = f2bf(acc[i][j][0] + bb);
                pk.y = f2bf(acc[i][j][1] + bb);
                pk.z = f2bf(acc[i][j][2] + bb);
                pk.w = f2bf(acc[i][j][3] + bb);
                *(ushort4*)&vto[(((size_t)bg * H_ + hh) * HD_ + hd) * S_ + s0] = pk;
            }
        }
    }
}

// ---------------------------------------------------------------------------
// Flash attention — EXACT round-8 structure (best measured: 80.8us, VGPR 60,
// no spill) + x2 literal-cur unroll (pure code motion: K/V LDS addresses
// become compile-time constants; __syncthreads kept — r11's asm-barrier
// counted-vmcnt pipeline regressed via spill/I-cache, reverted).
// 8 waves, QT=128, KVBLK=64, grid 512 (2 blocks/CU, 16 waves/CU). Wave pair
// (2qs, 2qs+1) covers qrows qs*32..+32, splits the 64-key tile (kw=(w&1)*32).
// Ps granules: even wave {0..3}^sw7, odd {4..7}^sw7 — disjoint. Epilogue:
// pair reduction via dead-LDS smem. Numerics: FP32 key-split add reorder
// only (proven r6/r8); RNE packs everywhere.
// ---------------------------------------------------------------------------
__global__ __launch_bounds__(512, 4)
void attn_mfma(const unsigned short* __restrict__ qmat,
               const unsigned short* __restrict__ kmat,
               const unsigned short* __restrict__ vtg,
               const unsigned char* __restrict__ msk, float* __restrict__ out) {
    const int h = blockIdx.x, qt = blockIdx.y, b = blockIdx.z;
    const int t = threadIdx.x, w = t >> 6, lane = t & 63;
    const int l15 = lane & 15, quad = lane >> 4;
    const int q0 = qt * 128;

    __shared__ __align__(16) char smem[49152];
    unsigned short* const Ksm = (unsigned short*)smem;            // [2][64*64]
    unsigned short* const Vsm = (unsigned short*)(smem + 16384);  // [2][64*64]
    unsigned short* const Psm = (unsigned short*)(smem + 32768);  // [128*64]

    const size_t bh = (size_t)b * S_ * D_ + (size_t)h * HD_;
    const unsigned short* __restrict__ qp = qmat + bh;
    const unsigned short* __restrict__ kp = kmat + bh;
    const unsigned short* __restrict__ vp = vtg + ((size_t)b * H_ + h) * HD_ * S_;
    const unsigned char* __restrict__ mb = msk + (size_t)b * S_ * S_;

    const int rs = lane >> 3, sslot = lane & 7;
    const int sg = (sslot ^ rs) * 8;         // staged global granule col (shorts)
    const int srow = w * 8 + rs;             // staging row 0..63 (8 rows/wave)

    const int qs = w >> 1;                   // q-substrip 0..3 (32 rows each)
    const int kw = (w & 1) * 32;             // wave's key half offset
    const int kst = w & 1;                   // key-half granule base for PV
    const int sw7 = l15 & 7;                 // row swizzle key (all rows &7)

    // Q fragments in registers (loop-invariant): 2 qrow strips x 2 d-halves
    bf16x8 qfr[2][2];
    #pragma unroll
    for (int nt = 0; nt < 2; ++nt)
        #pragma unroll
        for (int dk = 0; dk < 2; ++dk)
            qfr[nt][dk] = *(const bf16x8*)(qp +
                (size_t)(q0 + qs * 32 + nt * 16 + l15) * D_ + dk * 32 + quad * 8);

    f32x4 accO[2][4] = {};
    f32x4 lsA[2] = {};
    bf16x8 ones;
    #pragma unroll
    for (int i = 0; i < 8; ++i) ones[i] = (short)0x3F80;   // bf16 1.0

    // prologue: stage tile 0 into buffer 0 (one 16B DMA per thread per matrix)
    gload_lds16(kp + (size_t)srow * D_ + sg, Ksm + w * 8 * 64);
    gload_lds16(vp + (size_t)srow * S_ + sg, Vsm + w * 8 * 64);

#define ATTN_STEP(IT, CUR)                                                     \
    do {                                                                       \
        const int kt = (IT) * 64;                                              \
        __syncthreads();                                                       \
        unsigned mu[2][2];                                                     \
        _Pragma("unroll")                                                      \
        for (int nt = 0; nt < 2; ++nt) {                                       \
            const unsigned char* __restrict__ mrow =                           \
                mb + (size_t)(q0 + qs * 32 + nt * 16 + l15) * S_ + kt + kw;    \
            mu[nt][0] = *(const unsigned*)(mrow + quad * 4);                   \
            mu[nt][1] = *(const unsigned*)(mrow + 16 + quad * 4);              \
        }                                                                      \
        if ((IT) + 1 < 32) {                                                   \
            const int ktn = kt + 64;                                           \
            gload_lds16(kp + (size_t)(ktn + srow) * D_ + sg,                   \
                        Ksm + ((CUR) ^ 1) * 4096 + w * 8 * 64);                \
            gload_lds16(vp + (size_t)srow * S_ + ktn + sg,                     \
                        Vsm + ((CUR) ^ 1) * 4096 + w * 8 * 64);                \
        }                                                                      \
        f32x4 sc[2][2] = {};                                                   \
        _Pragma("unroll")                                                      \
        for (int dk = 0; dk < 2; ++dk) {                                       \
            bf16x8 kfr[2];                                                     \
            _Pragma("unroll")                                                  \
            for (int mt = 0; mt < 2; ++mt) {                                   \
                const int R = kw + mt * 16 + l15;                              \
                kfr[mt] = *(const bf16x8*)&Ksm[(CUR) * 4096 + R * 64 +         \
                                               (((dk * 4 + quad) ^ sw7) * 8)]; \
            }                                                                  \
            __builtin_amdgcn_s_setprio(1);                                     \
            _Pragma("unroll")                                                  \
            for (int nt = 0; nt < 2; ++nt)                                     \
                _Pragma("unroll")                                              \
                for (int mt = 0; mt < 2; ++mt)                                 \
                    sc[nt][mt] = __builtin_amdgcn_mfma_f32_16x16x32_bf16(      \
                        kfr[mt], qfr[nt][dk], sc[nt][mt], 0, 0, 0);            \
            __builtin_amdgcn_s_setprio(0);                                     \
        }                                                                      \
        _Pragma("unroll")                                                      \
        for (int nt = 0; nt < 2; ++nt) {                                       \
            const int qr = qs * 32 + nt * 16 + l15;                            \
            _Pragma("unroll")                                                  \
            for (int mt = 0; mt < 2; ++mt) {                                   \
                const int mtg = kst * 2 + mt;                                  \
                unsigned p0 = pack2bf(__builtin_amdgcn_exp2f(sc[nt][mt][0]),   \
                                      __builtin_amdgcn_exp2f(sc[nt][mt][1]));  \
                unsigned p1 = pack2bf(__builtin_amdgcn_exp2f(sc[nt][mt][2]),   \
                                      __builtin_amdgcn_exp2f(sc[nt][mt][3]));  \
                const unsigned m0 =                                            \
                    __builtin_amdgcn_perm(0u, mu[nt][mt], 0x01010000u);        \
                const unsigned m1 =                                            \
                    __builtin_amdgcn_perm(0u, mu[nt][mt], 0x03030202u);        \
                p0 = (m0 & 0x3F803F80u) | (~m0 & p0);                          \
                p1 = (m1 & 0x3F803F80u) | (~m1 & p1);                          \
                uint2 pk2; pk2.x = p0; pk2.y = p1;                             \
                *(uint2*)((char*)Psm + qr * 128 +                              \
                          (((2 * mtg + (quad >> 1)) ^ sw7) * 16) +             \
                          (quad & 1) * 8) = pk2;                               \
            }                                                                  \
        }                                                                      \
        {                                                                      \
            bf16x8 vfr[4];                                                     \
            _Pragma("unroll")                                                  \
            for (int dt = 0; dt < 4; ++dt) {                                   \
                const int R = dt * 16 + l15;                                   \
                vfr[dt] = *(const bf16x8*)&Vsm[(CUR) * 4096 + R * 64 +         \
                                               (((kst * 4 + quad) ^ sw7) * 8)];\
            }                                                                  \
            _Pragma("unroll")                                                  \
            for (int nt = 0; nt < 2; ++nt) {                                   \
                const int qr = qs * 32 + nt * 16 + l15;                        \
                bf16x8 pfr = *(const bf16x8*)((const char*)Psm + qr * 128 +    \
                                              (((kst * 4 + quad) ^ sw7) * 16));\
                __builtin_amdgcn_s_setprio(1);                                 \
                _Pragma("unroll")                                              \
                for (int dt = 0; dt < 4; ++dt)                                 \
                    accO[nt][dt] = __builtin_amdgcn_mfma_f32_16x16x32_bf16(    \
                        pfr, vfr[dt], accO[nt][dt], 0, 0, 0);                  \
                lsA[nt] = __builtin_amdgcn_mfma_f32_16x16x32_bf16(             \
                    pfr, ones, lsA[nt], 0, 0, 0);                              \
                __builtin_amdgcn_s_setprio(0);                                 \
            }                                                                  \
        }                                                                      \
    } while (0)

    for (int io = 0; io < 16; ++io) {
        ATTN_STEP(2 * io, 0);
        ATTN_STEP(2 * io + 1, 1);
    }
#undef ATTN_STEP

    // pair reduction: odd wave's partial accO/lsA -> even wave via smem
    // (Ks/Vs/Ps dead; 8 strips x 64 lanes x 20 floats = 40960B <= 49152B)
    __syncthreads();
    float* const Red = (float*)smem;
    if (w & 1) {
        #pragma unroll
        for (int nt = 0; nt < 2; ++nt) {
            const int pidx = ((qs * 2 + nt) * 64 + lane) * 20;
            #pragma unroll
            for (int dt = 0; dt < 4; ++dt)
                *(f32x4*)&Red[pidx + dt * 4] = accO[nt][dt];
            *(f32x4*)&Red[pidx + 16] = lsA[nt];
        }
    }
    __syncthreads();
    if (!(w & 1)) {
        float* __restrict__ ob = out + ((size_t)b * S_ + q0) * D_ + (size_t)h * HD_;
        #pragma unroll
        for (int nt = 0; nt < 2; ++nt) {
            const int pidx = ((qs * 2 + nt) * 64 + lane) * 20;
            #pragma unroll
            for (int dt = 0; dt < 4; ++dt)
                accO[nt][dt] += *(const f32x4*)&Red[pidx + dt * 4];
            lsA[nt] += *(const f32x4*)&Red[pidx + 16];

            #pragma unroll
            for (int r = 0; r < 4; ++r) {
                const float inv = 1.0f / lsA[nt][r];
                const int row = qs * 32 + nt * 16 + quad * 4 + r;
                #pragma unroll
                for (int dt = 0; dt < 4; ++dt)
                    ob[(size_t)row * D_ + dt * 16 + l15] = accO[nt][dt][r] * inv;
            }
        }
    }
}

extern "C" void kernel_launch(void* const* d_in, const int* in_sizes, int n_in,
                              void* d_out, int out_size, void* d_ws, size_t ws_size,
                              hipStream_t stream) {
    (void)in_sizes; (void)n_in; (void)out_size; (void)ws_size;
    const float* x    = (const float*)d_in[0];
    const int*   mask = (const int*)d_in[1];
    const float* Wq   = (const float*)d_in[2];
    const float* bq   = (const float*)d_in[3];
    const float* Wk   = (const float*)d_in[4];
    const float* bk   = (const float*)d_in[5];
    const float* Wv   = (const float*)d_in[6];
    const float* bv   = (const float*)d_in[7];
    float* out = (float*)d_out;

    const size_t M1 = (size_t)1024 * 1024;
    unsigned short* xb  = (unsigned short*)d_ws;      // 4M bf16
    unsigned short* wtb = xb + 4 * M1;                // 3M bf16
    unsigned short* qb  = wtb + 3 * M1;               // 4M bf16
    unsigned short* kb  = qb + 4 * M1;                // 4M bf16
    unsigned short* vtb = kb + 4 * M1;                // 4M bf16 (transposed V)
    unsigned char*  mk  = (unsigned char*)(vtb + 4 * M1);  // 8M u8 (0xFF/0x00)

    prep<<<4864, 256, 0, stream>>>(x, xb, mask, mk, Wq, Wk, Wv, wtb);
    qkv_gemm<<<dim3(24, 32), 512, 0, stream>>>(xb, wtb, bq, bk, bv, qb, kb, vtb);
    attn_mfma<<<dim3(16, 16, 2), 512, 0, stream>>>(qb, kb, vtb, mk, out);
}

// Round 13
// 209.313 us; speedup vs baseline: 2.4748x; 1.0167x over previous
//
#include <hip/hip_runtime.h>
#include <cstdint>
#include <cstddef>

static constexpr int B_ = 2, S_ = 2048, D_ = 1024, H_ = 16, HD_ = 64;

typedef float f32x4 __attribute__((ext_vector_type(4)));
typedef short bf16x8 __attribute__((ext_vector_type(8)));

__device__ __forceinline__ unsigned short f2bf(float f) {
    union { float f; unsigned int u; } v; v.f = f;
    unsigned int r = v.u + 0x7FFFu + ((v.u >> 16) & 1u);   // RNE
    return (unsigned short)(r >> 16);
}

// 5-op RNE pair pack. Bit-identical to f2bf(a) | f2bf(b)<<16. NO hardware
// cvt_pk (round-2 failure: v_cvt_pk_bf16_f32 is not RNE-equivalent).
__device__ __forceinline__ unsigned pack2bf(float a, float b) {
    union { float f; unsigned u; } va, vb; va.f = a; vb.f = b;
    unsigned ra = va.u + 0x7FFFu + ((va.u >> 16) & 1u);
    unsigned rb = vb.u + 0x7FFFu + ((vb.u >> 16) & 1u);
    return __builtin_amdgcn_perm(rb, ra, 0x07060302u);
}

// async global->LDS, 16B per lane. LDS dest = wave-uniform base + lane*16.
__device__ __forceinline__ void gload_lds16(const void* g, void* l) {
    __builtin_amdgcn_global_load_lds(
        (const __attribute__((address_space(1))) void*)g,
        (__attribute__((address_space(3))) void*)l, 16, 0, 0);
}

// ---------------------------------------------------------------------------
// Fused prep: [0,2048) cast x->bf16 | [2048,4096) mask int32->u8 (0xFF/0x00) |
// [4096,4864) W transpose+cast. (proven)
// ---------------------------------------------------------------------------
__global__ __launch_bounds__(256)
void prep(const float* __restrict__ x, unsigned short* __restrict__ xo,
          const int* __restrict__ m, unsigned char* __restrict__ mo,
          const float* __restrict__ Wq, const float* __restrict__ Wk,
          const float* __restrict__ Wv, unsigned short* __restrict__ wt) {
    __shared__ unsigned short Ts[64][72];
    const int bid = blockIdx.x, t = threadIdx.x;
    if (bid < 2048) {
        size_t i = ((size_t)bid * 256 + t) * 8;
        float4 a = *(const float4*)(x + i);
        float4 c = *(const float4*)(x + i + 4);
        uint4 r;
        r.x = pack2bf(a.x, a.y); r.y = pack2bf(a.z, a.w);
        r.z = pack2bf(c.x, c.y); r.w = pack2bf(c.z, c.w);
        *(uint4*)(xo + i) = r;
    } else if (bid < 4096) {
        size_t i = ((size_t)(bid - 2048) * 256 + t) * 16;
        uint4 r;
        unsigned w[4];
        #pragma unroll
        for (int g = 0; g < 4; ++g) {
            int4 v = *(const int4*)(m + i + g * 4);
            w[g] = (v.x ? 0xFFu : 0u) | (v.y ? 0xFF00u : 0u) |
                   (v.z ? 0xFF0000u : 0u) | (v.w ? 0xFF000000u : 0u);
        }
        r.x = w[0]; r.y = w[1]; r.z = w[2]; r.w = w[3];
        *(uint4*)(mo + i) = r;
    } else {
        const int tid = bid - 4096;            // 0..767
        const int mat = tid >> 8, tile = tid & 255;
        const float* __restrict__ W = (mat == 0) ? Wq : (mat == 1) ? Wk : Wv;
        unsigned short* __restrict__ o = wt + (size_t)mat * D_ * D_;
        const int n0 = (tile & 15) * 64, k0 = (tile >> 4) * 64;
        {
            const int nl = t & 63, kb = t >> 6;
            #pragma unroll
            for (int i = 0; i < 16; ++i) {
                int k = kb + i * 4;
                Ts[nl][k] = f2bf(W[(size_t)(k0 + k) * D_ + n0 + nl]);
            }
        }
        __syncthreads();
        {
            const int kl = t & 63, nb = t >> 6;
            #pragma unroll
            for (int i = 0; i < 16; ++i) {
                int n = nb + i * 4;
                o[(size_t)(n0 + n) * D_ + k0 + kl] = Ts[n][kl];
            }
        }
    }
}

// ---------------------------------------------------------------------------
// QKV GEMM, bf16 MFMA 16x16x32. 128x128 tile, BK=32, double-buffered DMA.
// 512 threads (8 waves, wave-tile 64x32), 24 waves/CU. (round-5, proven)
// ---------------------------------------------------------------------------
__global__ __launch_bounds__(512)
void qkv_gemm(const unsigned short* __restrict__ xb, const unsigned short* __restrict__ wt,
              const float* __restrict__ bq, const float* __restrict__ bk,
              const float* __restrict__ bv,
              unsigned short* __restrict__ qo, unsigned short* __restrict__ ko,
              unsigned short* __restrict__ vto) {
    const int bx = blockIdx.x;            // 0..23: mat*8 + ntile
    const int by = blockIdx.y;            // 0..31: mtile
    const int mat = bx >> 3;
    const int ncol0 = (bx & 7) * 128;
    const float* __restrict__ bias = (mat == 0) ? bq : (mat == 1) ? bk : bv;
    const unsigned short* __restrict__ Wm = wt + (size_t)mat * D_ * D_;

    __shared__ unsigned short As[2][128 * 32];
    __shared__ unsigned short Bs[2][128 * 32];

    const int t = threadIdx.x;
    const int w = t >> 6, lane = t & 63;
    const int l15 = lane & 15, quad = lane >> 4;
    const int mw = (w >> 2) * 64, nw = (w & 3) * 32;   // wave tile 64x32
    const int rowBase = by * 128;

    const int r16 = lane >> 2;                       // 0..15
    const int sslot = lane & 3;
    const int sg = (sslot ^ ((r16 >> 1) & 3)) * 8;   // staged global col (shorts)
    const int srow = w * 16 + r16;                   // staging row 0..127
    const int rcol = (quad ^ ((l15 >> 1) & 3)) * 8;  // fragment read col (shorts)

    f32x4 acc[4][2] = {};

    gload_lds16(xb + (size_t)(rowBase + srow) * D_ + sg, &As[0][w * 16 * 32]);
    gload_lds16(Wm + (size_t)(ncol0 + srow) * D_ + sg, &Bs[0][w * 16 * 32]);

    for (int it = 0; it < 32; ++it) {
        const int cur = it & 1;
        __syncthreads();
        if (it + 1 < 32) {
            const int ktn = (it + 1) * 32;
            gload_lds16(xb + (size_t)(rowBase + srow) * D_ + ktn + sg,
                        &As[cur ^ 1][w * 16 * 32]);
            gload_lds16(Wm + (size_t)(ncol0 + srow) * D_ + ktn + sg,
                        &Bs[cur ^ 1][w * 16 * 32]);
        }

        bf16x8 a[4], b[2];
        #pragma unroll
        for (int i = 0; i < 4; ++i)
            a[i] = *(const bf16x8*)&As[cur][(mw + i * 16 + l15) * 32 + rcol];
        #pragma unroll
        for (int j = 0; j < 2; ++j)
            b[j] = *(const bf16x8*)&Bs[cur][(nw + j * 16 + l15) * 32 + rcol];
        #pragma unroll
        for (int i = 0; i < 4; ++i)
            #pragma unroll
            for (int j = 0; j < 2; ++j)
                acc[i][j] = __builtin_amdgcn_mfma_f32_16x16x32_bf16(a[i], b[j], acc[i][j], 0, 0, 0);
    }

    if (mat < 2) {
        unsigned short* __restrict__ O = (mat == 0) ? qo : ko;
        const float osc = (mat == 0) ? 0.18033688011112443f : 1.0f;  // 0.125*log2(e)
        #pragma unroll
        for (int j = 0; j < 2; ++j) {
            const int col = ncol0 + nw + j * 16 + l15;
            const float bb = bias[col];
            #pragma unroll
            for (int i = 0; i < 4; ++i)
                #pragma unroll
                for (int r = 0; r < 4; ++r) {
                    const int m = rowBase + mw + i * 16 + quad * 4 + r;
                    O[(size_t)m * D_ + col] = f2bf((acc[i][j][r] + bb) * osc);
                }
        }
    } else {
        #pragma unroll
        for (int j = 0; j < 2; ++j) {
            const int col = ncol0 + nw + j * 16 + l15;
            const float bb = bias[col];
            const int hh = col >> 6, hd = col & 63;
            #pragma unroll
            for (int i = 0; i < 4; ++i) {
                const int m0 = rowBase + mw + i * 16 + quad * 4;
                const int bg = m0 >> 11, s0 = m0 & 2047;
                ushort4 pk;
                pk.x = f2bf(acc[i][j][0] + bb);
                pk.y = f2bf(acc[i][j][1] + bb);
                pk.z = f2bf(acc[i][j][2] + bb);
                pk.w = f2bf(acc[i][j][3] + bb);
                *(ushort4*)&vto[(((size_t)bg * H_ + hh) * HD_ + hd) * S_ + s0] = pk;
            }
        }
    }
}

// ---------------------------------------------------------------------------
// Flash attention — EXACT round-8 kernel (best measured: 80.8us, VGPR 60,
// no spill). Runtime-cur loop (r12's x2 literal-cur unroll cost +6.4us via
// code size + minor spill — reverted). 8 waves (512 thr), QT=128, KVBLK=64,
// grid 512 (2 blocks/CU, 16 waves/CU). Wave pair (2qs, 2qs+1) covers qrows
// qs*32..+32 and splits the 64-key tile (kw=(w&1)*32): per-wave-iter LDS
// read = 12KB. Ps granules: even wave {0..3}^sw7, odd {4..7}^sw7 (disjoint).
// Epilogue: pair reduction via dead-LDS smem. launch_bounds(512,4): cap 128
// >> 60 used (r6/r9: never chase occupancy with the 2nd arg).
// Numerics: FP32 key-split add reorder only; RNE packs everywhere.
// ---------------------------------------------------------------------------
__global__ __launch_bounds__(512, 4)
void attn_mfma(const unsigned short* __restrict__ qmat,
               const unsigned short* __restrict__ kmat,
               const unsigned short* __restrict__ vtg,
               const unsigned char* __restrict__ msk, float* __restrict__ out) {
    const int h = blockIdx.x, qt = blockIdx.y, b = blockIdx.z;
    const int t = threadIdx.x, w = t >> 6, lane = t & 63;
    const int l15 = lane & 15, quad = lane >> 4;
    const int q0 = qt * 128;

    __shared__ __align__(16) char smem[49152];
    unsigned short* const Ksm = (unsigned short*)smem;            // [2][64*64]
    unsigned short* const Vsm = (unsigned short*)(smem + 16384);  // [2][64*64]
    unsigned short* const Psm = (unsigned short*)(smem + 32768);  // [128*64]

    const size_t bh = (size_t)b * S_ * D_ + (size_t)h * HD_;
    const unsigned short* __restrict__ qp = qmat + bh;
    const unsigned short* __restrict__ kp = kmat + bh;
    const unsigned short* __restrict__ vp = vtg + ((size_t)b * H_ + h) * HD_ * S_;
    const unsigned char* __restrict__ mb = msk + (size_t)b * S_ * S_;

    const int rs = lane >> 3, sslot = lane & 7;
    const int sg = (sslot ^ rs) * 8;         // staged global granule col (shorts)
    const int srow = w * 8 + rs;             // staging row 0..63 (8 rows/wave)

    const int qs = w >> 1;                   // q-substrip 0..3 (32 rows each)
    const int kw = (w & 1) * 32;             // wave's key half offset
    const int kst = w & 1;                   // key-half granule base for PV
    const int sw7 = l15 & 7;                 // row swizzle key (all rows &7)

    // Q fragments in registers (loop-invariant): 2 qrow strips x 2 d-halves
    bf16x8 qfr[2][2];
    #pragma unroll
    for (int nt = 0; nt < 2; ++nt)
        #pragma unroll
        for (int dk = 0; dk < 2; ++dk)
            qfr[nt][dk] = *(const bf16x8*)(qp +
                (size_t)(q0 + qs * 32 + nt * 16 + l15) * D_ + dk * 32 + quad * 8);

    f32x4 accO[2][4] = {};
    f32x4 lsA[2] = {};
    bf16x8 ones;
    #pragma unroll
    for (int i = 0; i < 8; ++i) ones[i] = (short)0x3F80;   // bf16 1.0

    // prologue: stage tile 0 into buffer 0 (one 16B DMA per thread per matrix)
    gload_lds16(kp + (size_t)srow * D_ + sg, Ksm + w * 8 * 64);
    gload_lds16(vp + (size_t)srow * S_ + sg, Vsm + w * 8 * 64);

    for (int it = 0; it < 32; ++it) {
        const int cur = it & 1;
        const int kt = it * 64;
        __syncthreads();   // buf cur DMA drained; readers of buf cur^1 done

        // 1) mask loads first (vmcnt FIFO: waiting on these won't drain DMA)
        unsigned mu[2][2];
        #pragma unroll
        for (int nt = 0; nt < 2; ++nt) {
            const unsigned char* __restrict__ mrow =
                mb + (size_t)(q0 + qs * 32 + nt * 16 + l15) * S_ + kt + kw;
            mu[nt][0] = *(const unsigned*)(mrow + quad * 4);
            mu[nt][1] = *(const unsigned*)(mrow + 16 + quad * 4);
        }

        // 2) prefetch next tile into the other buffer
        if (it + 1 < 32) {
            const int ktn = kt + 64;
            gload_lds16(kp + (size_t)(ktn + srow) * D_ + sg,
                        Ksm + (cur ^ 1) * 4096 + w * 8 * 64);
            gload_lds16(vp + (size_t)srow * S_ + ktn + sg,
                        Vsm + (cur ^ 1) * 4096 + w * 8 * 64);
        }

        // 3) S^T = K·Q^T : wave's 32 keys (2 m-tiles) x 32 qrows (2 n-strips)
        f32x4 sc[2][2] = {};   // [nt][mt]
        #pragma unroll
        for (int dk = 0; dk < 2; ++dk) {
            bf16x8 kfr[2];
            #pragma unroll
            for (int mt = 0; mt < 2; ++mt) {
                const int R = kw + mt * 16 + l15;
                kfr[mt] = *(const bf16x8*)&Ksm[cur * 4096 + R * 64 +
                                               (((dk * 4 + quad) ^ sw7) * 8)];
            }
            __builtin_amdgcn_s_setprio(1);
            #pragma unroll
            for (int nt = 0; nt < 2; ++nt)
                #pragma unroll
                for (int mt = 0; mt < 2; ++mt)
                    sc[nt][mt] = __builtin_amdgcn_mfma_f32_16x16x32_bf16(
                        kfr[mt], qfr[nt][dk], sc[nt][mt], 0, 0, 0);
            __builtin_amdgcn_s_setprio(0);
        }

        // 4) exp2 + pack + perm/bfi mask-merge + swizzled P^T store
        //    (granules {0..3}^sw7 even wave / {4..7}^sw7 odd wave: disjoint)
        #pragma unroll
        for (int nt = 0; nt < 2; ++nt) {
            const int qr = qs * 32 + nt * 16 + l15;
            #pragma unroll
            for (int mt = 0; mt < 2; ++mt) {
                const int mtg = kst * 2 + mt;
                unsigned p0 = pack2bf(__builtin_amdgcn_exp2f(sc[nt][mt][0]),
                                      __builtin_amdgcn_exp2f(sc[nt][mt][1]));
                unsigned p1 = pack2bf(__builtin_amdgcn_exp2f(sc[nt][mt][2]),
                                      __builtin_amdgcn_exp2f(sc[nt][mt][3]));
                const unsigned m0 = __builtin_amdgcn_perm(0u, mu[nt][mt], 0x01010000u);
                const unsigned m1 = __builtin_amdgcn_perm(0u, mu[nt][mt], 0x03030202u);
                p0 = (m0 & 0x3F803F80u) | (~m0 & p0);   // v_bfi: masked -> bf16 1.0
                p1 = (m1 & 0x3F803F80u) | (~m1 & p1);
                uint2 pk2; pk2.x = p0; pk2.y = p1;
                *(uint2*)((char*)Psm + qr * 128 +
                          (((2 * mtg + (quad >> 1)) ^ sw7) * 16) + (quad & 1) * 8) = pk2;
            }
        }

        // 5) O += P·V over the wave's 32 keys ; lsum += P·1
        {
            bf16x8 vfr[4];
            #pragma unroll
            for (int dt = 0; dt < 4; ++dt) {
                const int R = dt * 16 + l15;
                vfr[dt] = *(const bf16x8*)&Vsm[cur * 4096 + R * 64 +
                                               (((kst * 4 + quad) ^ sw7) * 8)];
            }
            #pragma unroll
            for (int nt = 0; nt < 2; ++nt) {
                const int qr = qs * 32 + nt * 16 + l15;
                bf16x8 pfr = *(const bf16x8*)((const char*)Psm + qr * 128 +
                                              (((kst * 4 + quad) ^ sw7) * 16));
                __builtin_amdgcn_s_setprio(1);
                #pragma unroll
                for (int dt = 0; dt < 4; ++dt)
                    accO[nt][dt] = __builtin_amdgcn_mfma_f32_16x16x32_bf16(
                        pfr, vfr[dt], accO[nt][dt], 0, 0, 0);
                lsA[nt] = __builtin_amdgcn_mfma_f32_16x16x32_bf16(pfr, ones, lsA[nt], 0, 0, 0);
                __builtin_amdgcn_s_setprio(0);
            }
        }
    }

    // pair reduction: odd wave's partial accO/lsA -> even wave via smem
    // (Ks/Vs/Ps dead; 8 strips x 64 lanes x 20 floats = 40960B <= 49152B)
    __syncthreads();
    float* const Red = (float*)smem;
    if (w & 1) {
        #pragma unroll
        for (int nt = 0; nt < 2; ++nt) {
            const int pidx = ((qs * 2 + nt) * 64 + lane) * 20;
            #pragma unroll
            for (int dt = 0; dt < 4; ++dt)
                *(f32x4*)&Red[pidx + dt * 4] = accO[nt][dt];
            *(f32x4*)&Red[pidx + 16] = lsA[nt];
        }
    }
    __syncthreads();
    if (!(w & 1)) {
        float* __restrict__ ob = out + ((size_t)b * S_ + q0) * D_ + (size_t)h * HD_;
        #pragma unroll
        for (int nt = 0; nt < 2; ++nt) {
            const int pidx = ((qs * 2 + nt) * 64 + lane) * 20;
            #pragma unroll
            for (int dt = 0; dt < 4; ++dt)
                accO[nt][dt] += *(const f32x4*)&Red[pidx + dt * 4];
            lsA[nt] += *(const f32x4*)&Red[pidx + 16];

            #pragma unroll
            for (int r = 0; r < 4; ++r) {
                const float inv = 1.0f / lsA[nt][r];
                const int row = qs * 32 + nt * 16 + quad * 4 + r;
                #pragma unroll
                for (int dt = 0; dt < 4; ++dt)
                    ob[(size_t)row * D_ + dt * 16 + l15] = accO[nt][dt][r] * inv;
            }
        }
    }
}

extern "C" void kernel_launch(void* const* d_in, const int* in_sizes, int n_in,
                              void* d_out, int out_size, void* d_ws, size_t ws_size,
                              hipStream_t stream) {
    (void)in_sizes; (void)n_in; (void)out_size; (void)ws_size;
    const float* x    = (const float*)d_in[0];
    const int*   mask = (const int*)d_in[1];
    const float* Wq   = (const float*)d_in[2];
    const float* bq   = (const float*)d_in[3];
    const float* Wk   = (const float*)d_in[4];
    const float* bk   = (const float*)d_in[5];
    const float* Wv   = (const float*)d_in[6];
    const float* bv   = (const float*)d_in[7];
    float* out = (float*)d_out;

    const size_t M1 = (size_t)1024 * 1024;
    unsigned short* xb  = (unsigned short*)d_ws;      // 4M bf16
    unsigned short* wtb = xb + 4 * M1;                // 3M bf16
    unsigned short* qb  = wtb + 3 * M1;               // 4M bf16
    unsigned short* kb  = qb + 4 * M1;                // 4M bf16
    unsigned short* vtb = kb + 4 * M1;                // 4M bf16 (transposed V)
    unsigned char*  mk  = (unsigned char*)(vtb + 4 * M1);  // 8M u8 (0xFF/0x00)

    prep<<<4864, 256, 0, stream>>>(x, xb, mask, mk, Wq, Wk, Wv, wtb);
    qkv_gemm<<<dim3(24, 32), 512, 0, stream>>>(xb, wtb, bq, bk, bv, qb, kb, vtb);
    attn_mfma<<<dim3(16, 16, 2), 512, 0, stream>>>(qb, kb, vtb, mk, out);
}